// Round 2
// baseline (417.621 us; speedup 1.0000x reference)
//
#include <hip/hip_runtime.h>
#include <cstdint>

// ---------------------------------------------------------------------------
// GQA cross-attention, bf16-MFMA pipeline:
//   cast -> Wt transposes -> QKV GEMMs (fp32 out) -> RoPE/repack (bf16)
//   -> flash attention (swapped-QK^T, lane-local softmax) -> output GEMM
// ---------------------------------------------------------------------------

typedef __bf16 bf16x8 __attribute__((ext_vector_type(8)));
typedef float f32x4 __attribute__((ext_vector_type(4)));

#define MFMA16(a, b, c) __builtin_amdgcn_mfma_f32_16x16x32_bf16((a), (b), (c), 0, 0, 0)

constexpr int Bc = 2, TQc = 2048, TKc = 2048, Dc = 1024, Hc = 16, Gc = 4, HDc = 64;

__device__ __forceinline__ ushort f2bf(float x) {  // RNE f32 -> bf16 bits
  uint32_t u = __builtin_bit_cast(uint32_t, x);
  u += 0x7fffu + ((u >> 16) & 1u);
  return (ushort)(u >> 16);
}

__device__ __forceinline__ void async_lds16(void* lds, const void* g) {
  // wave-uniform LDS base; lane i lands at base + 16*i (guide §5)
  __builtin_amdgcn_global_load_lds((const __attribute__((address_space(1))) uint32_t*)g,
                                   (__attribute__((address_space(3))) uint32_t*)lds,
                                   16, 0, 0);
}

// ---------------- elementwise f32 -> bf16 cast (vectorized x4) -------------
__global__ __launch_bounds__(256) void cast_bf16_k(const float* __restrict__ s,
                                                   ushort* __restrict__ d, int n4) {
  int i = blockIdx.x * 256 + threadIdx.x;
  if (i >= n4) return;
  float4 v = reinterpret_cast<const float4*>(s)[i];
  ushort4 o;
  o.x = f2bf(v.x); o.y = f2bf(v.y); o.z = f2bf(v.z); o.w = f2bf(v.w);
  reinterpret_cast<ushort4*>(d)[i] = o;
}

// ---------------- W [R][C] f32  ->  Wt [C][R] bf16 (64x64 LDS tiles) -------
__global__ __launch_bounds__(256) void wtrans_k(const float* __restrict__ src,
                                                ushort* __restrict__ dst, int R, int C) {
  __shared__ float t[64][65];
  int r0 = blockIdx.y * 64, c0 = blockIdx.x * 64;
  int tx = threadIdx.x & 63, ty = threadIdx.x >> 6;
#pragma unroll
  for (int i = 0; i < 16; ++i) {
    int r = i * 4 + ty;
    t[r][tx] = src[(size_t)(r0 + r) * C + c0 + tx];
  }
  __syncthreads();
#pragma unroll
  for (int i = 0; i < 16; ++i) {
    int c = i * 4 + ty;
    dst[(size_t)(c0 + c) * R + r0 + tx] = f2bf(t[tx][c]);
  }
}

// ------- v f32 [b][t][g*64+d] -> Vt bf16 [b][g][d][t]  (PV B-operand) ------
__global__ __launch_bounds__(256) void vtrans_k(const float* __restrict__ v,
                                                ushort* __restrict__ Vt) {
  __shared__ float t[64][65];
  int t0 = blockIdx.x * 64, g = blockIdx.y, b = blockIdx.z;
  int tx = threadIdx.x & 63, ty = threadIdx.x >> 6;
#pragma unroll
  for (int i = 0; i < 16; ++i) {
    int tl = i * 4 + ty;
    t[tl][tx] = v[((size_t)b * TKc + t0 + tl) * (Gc * HDc) + g * HDc + tx];
  }
  __syncthreads();
#pragma unroll
  for (int i = 0; i < 16; ++i) {
    int dd = i * 4 + ty;
    Vt[((size_t)(b * Gc + g) * HDc + dd) * TKc + t0 + tx] = f2bf(t[tx][dd]);
  }
}

// ------- RoPE + repack: q f32 [b][t][h*64+d] -> Qb bf16 [b][h][t][d] -------
// NOTE: folds the attention scale 1/sqrt(64)=0.125 into Q (exact in bf16).
__global__ __launch_bounds__(256) void ropeq_k(const float* __restrict__ q,
                                               ushort* __restrict__ Qb) {
  int idx = blockIdx.x * 256 + threadIdx.x;  // i(5) t(11) h(4) b(1)
  int i = idx & 31;
  int t = (idx >> 5) & (TQc - 1);
  int h = (idx >> 16) & (Hc - 1);
  int b = idx >> 20;
  float ang = (float)t * __expf(-0.28782313662425572f * (float)i);  // -ln(1e4)/32
  float sn, cs;
  __sincosf(ang, &sn, &cs);
  float2 x = *reinterpret_cast<const float2*>(&q[((size_t)b * TQc + t) * Dc + h * HDc + 2 * i]);
  ushort2 o;
  o.x = f2bf((x.x * cs - x.y * sn) * 0.125f);
  o.y = f2bf((x.x * sn + x.y * cs) * 0.125f);
  *reinterpret_cast<ushort2*>(&Qb[(((size_t)(b * Hc + h)) * TQc + t) * HDc + 2 * i]) = o;
}

__global__ __launch_bounds__(256) void ropek_k(const float* __restrict__ k,
                                               ushort* __restrict__ Kb) {
  int idx = blockIdx.x * 256 + threadIdx.x;  // i(5) t(11) g(2) b(1)
  int i = idx & 31;
  int t = (idx >> 5) & (TKc - 1);
  int g = (idx >> 16) & (Gc - 1);
  int b = idx >> 18;
  float ang = (float)t * __expf(-0.28782313662425572f * (float)i);
  float sn, cs;
  __sincosf(ang, &sn, &cs);
  float2 x = *reinterpret_cast<const float2*>(&k[((size_t)b * TKc + t) * (Gc * HDc) + g * HDc + 2 * i]);
  ushort2 o;
  o.x = f2bf(x.x * cs - x.y * sn);
  o.y = f2bf(x.x * sn + x.y * cs);
  *reinterpret_cast<ushort2*>(&Kb[(((size_t)(b * Gc + g)) * TKc + t) * HDc + 2 * i]) = o;
}

// ------- C[M][N] f32 = A[M][K]bf16 * Bt[N][K]bf16^T + bias[N] --------------
// 128x128 tile, BK=32, 4 waves (2x2), global_load_lds width-16 staging.
__global__ __launch_bounds__(256) void gemm_bt_bias(const ushort* __restrict__ A,
                                                    const ushort* __restrict__ Bt,
                                                    const float* __restrict__ bias,
                                                    float* __restrict__ C,
                                                    int M, int N, int K) {
  __shared__ __attribute__((aligned(16))) ushort sA[128 * 32];
  __shared__ __attribute__((aligned(16))) ushort sB[128 * 32];
  const int tid = threadIdx.x;
  const int lane = tid & 63, wid = tid >> 6;
  const int l15 = lane & 15, l4 = lane >> 4;
  const int m0 = blockIdx.y * 128, n0 = blockIdx.x * 128;
  const int wr = (wid >> 1) * 64, wc = (wid & 1) * 64;

  const f32x4 z = {0.f, 0.f, 0.f, 0.f};
  f32x4 acc[4][4];
#pragma unroll
  for (int mi = 0; mi < 4; ++mi)
#pragma unroll
    for (int ni = 0; ni < 4; ++ni) acc[mi][ni] = z;

  for (int k0 = 0; k0 < K; k0 += 32) {
#pragma unroll
    for (int i = 0; i < 2; ++i) {
      int c = wid * 2 + i;            // 1KB chunk index (8 per tile)
      int tb = c * 1024 + lane * 16;  // byte within tile; 64B per row (BK*2)
      int row = tb >> 6;
      int cole = (tb & 63) >> 1;
      async_lds16((char*)sA + c * 1024, A + (size_t)(m0 + row) * K + k0 + cole);
      async_lds16((char*)sB + c * 1024, Bt + (size_t)(n0 + row) * K + k0 + cole);
    }
    __syncthreads();
    bf16x8 af[4], bfr[4];
#pragma unroll
    for (int mi = 0; mi < 4; ++mi)
      af[mi] = *reinterpret_cast<const bf16x8*>(&sA[(wr + mi * 16 + l15) * 32 + l4 * 8]);
#pragma unroll
    for (int ni = 0; ni < 4; ++ni)
      bfr[ni] = *reinterpret_cast<const bf16x8*>(&sB[(wc + ni * 16 + l15) * 32 + l4 * 8]);
#pragma unroll
    for (int mi = 0; mi < 4; ++mi)
#pragma unroll
      for (int ni = 0; ni < 4; ++ni)
        acc[mi][ni] = MFMA16(af[mi], bfr[ni], acc[mi][ni]);
    __syncthreads();
  }

#pragma unroll
  for (int mi = 0; mi < 4; ++mi)
#pragma unroll
    for (int ni = 0; ni < 4; ++ni) {
      int col = n0 + wc + ni * 16 + l15;
      float bv = bias[col];
      int rowb = m0 + wr + mi * 16 + l4 * 4;  // D: row=(l>>4)*4+r, col=l&15
#pragma unroll
      for (int r = 0; r < 4; ++r)
        C[(size_t)(rowb + r) * N + col] = acc[mi][ni][r] + bv;
    }
}

// ------- flash attention, swapped-QK^T (S^T = K*Q^T) -----------------------
// Qb[b][h][t][64] (pre-scaled by 0.125), Kb[b][g][t][64], Vt[b][g][64][t].
// 4 independent waves/block (NO barriers), 16 q-rows/wave, KV tiles of 64.
// Per lane: q = q0 + l15; scores for keys nf*16 + l4*4 + r  (lane-local row).
__global__ __launch_bounds__(256) void attn_k(const ushort* __restrict__ Qg,
                                              const ushort* __restrict__ Kg,
                                              const ushort* __restrict__ Vg,
                                              ushort* __restrict__ Ob) {
  __shared__ __attribute__((aligned(16))) ushort sP[4][16 * 64];  // per-wave P
  const int lane = threadIdx.x & 63, wid = threadIdx.x >> 6;
  const int l15 = lane & 15, l4 = lane >> 4;
  const int b = blockIdx.z, h = blockIdx.y, g = h >> 2;  // H/G = 4
  const int q0 = blockIdx.x * 64 + wid * 16;
  const ushort* Qp = Qg + ((size_t)(b * Hc + h)) * TQc * HDc;
  const ushort* Kp = Kg + ((size_t)(b * Gc + g)) * TKc * HDc;
  const ushort* Vp = Vg + ((size_t)(b * Gc + g)) * HDc * TKc;
  char* pb = (char*)&sP[wid][0];
  const int rx = (l15 & 7) << 4;  // LDS XOR swizzle for this lane's row

  // Q (B operand): col n=l15 -> q=q0+l15, k=l4*8+j -> d
  bf16x8 bq0 = *reinterpret_cast<const bf16x8*>(Qp + (size_t)(q0 + l15) * HDc + l4 * 8);
  bf16x8 bq1 = *reinterpret_cast<const bf16x8*>(Qp + (size_t)(q0 + l15) * HDc + 32 + l4 * 8);

  float m = -INFINITY, l = 0.f;
  const f32x4 z = {0.f, 0.f, 0.f, 0.f};
  f32x4 accO[4] = {z, z, z, z};

  for (int kt = 0; kt < TKc / 64; ++kt) {
    const ushort* Kt = Kp + (size_t)kt * 64 * HDc;
    // K (A operand): row m=l15 -> key=nf*16+l15, k=l4*8+j -> d
    f32x4 s[4] = {z, z, z, z};
#pragma unroll
    for (int nf = 0; nf < 4; ++nf) {
      const ushort* kr = Kt + (size_t)(nf * 16 + l15) * HDc + l4 * 8;
      s[nf] = MFMA16(*reinterpret_cast<const bf16x8*>(kr), bq0, s[nf]);
      s[nf] = MFMA16(*reinterpret_cast<const bf16x8*>(kr + 32), bq1, s[nf]);
    }
    // V fragments issued early (latency hidden under softmax): B[k=key][n=d]
    bf16x8 va[4][2];
#pragma unroll
    for (int df = 0; df < 4; ++df)
#pragma unroll
      for (int kk = 0; kk < 2; ++kk)
        va[df][kk] = *reinterpret_cast<const bf16x8*>(
            Vp + (size_t)(df * 16 + l15) * TKc + kt * 64 + kk * 32 + l4 * 8);

    // ---- lane-local softmax (one q-row per lane) ----
    float pm = fmaxf(fmaxf(fmaxf(s[0][0], s[0][1]), fmaxf(s[0][2], s[0][3])),
                     fmaxf(fmaxf(s[1][0], s[1][1]), fmaxf(s[1][2], s[1][3])));
    pm = fmaxf(pm, fmaxf(fmaxf(fmaxf(s[2][0], s[2][1]), fmaxf(s[2][2], s[2][3])),
                         fmaxf(fmaxf(s[3][0], s[3][1]), fmaxf(s[3][2], s[3][3]))));
    pm = fmaxf(pm, __shfl_xor(pm, 16));
    pm = fmaxf(pm, __shfl_xor(pm, 32));
    if (!__all(pm - m <= 8.f)) {  // T13 defer-max: rescale only on real growth
      float mn = fmaxf(m, pm);
      float sc = __expf(m - mn);
      m = mn;
      l *= sc;
#pragma unroll
      for (int df = 0; df < 4; ++df) accO[df] *= sc;
    }
    float ps = 0.f;
#pragma unroll
    for (int nf = 0; nf < 4; ++nf)
#pragma unroll
      for (int r = 0; r < 4; ++r) {
        float p = __expf(s[nf][r] - m);
        s[nf][r] = p;
        ps += p;
      }
    ps += __shfl_xor(ps, 16);
    ps += __shfl_xor(ps, 32);
    l += ps;

    // ---- P -> LDS (row q=l15): 4x ds_write_b64, XOR-swizzled ----
#pragma unroll
    for (int nf = 0; nf < 4; ++nf) {
      uint2 w;
      w.x = (uint)f2bf(s[nf][0]) | ((uint)f2bf(s[nf][1]) << 16);
      w.y = (uint)f2bf(s[nf][2]) | ((uint)f2bf(s[nf][3]) << 16);
      *reinterpret_cast<uint2*>(pb + l15 * 128 + ((nf * 32 + l4 * 8) ^ rx)) = w;
    }
    // ---- PV: A = P[q=l15][k=key], B = V^T[key][d=l15] ----
    bf16x8 ap0 = *reinterpret_cast<const bf16x8*>(pb + l15 * 128 + ((l4 * 16) ^ rx));
    bf16x8 ap1 = *reinterpret_cast<const bf16x8*>(pb + l15 * 128 + ((64 + l4 * 16) ^ rx));
#pragma unroll
    for (int df = 0; df < 4; ++df)
      accO[df] = MFMA16(ap1, va[df][1], MFMA16(ap0, va[df][0], accO[df]));
  }

  // epilogue: lane holds O[q=q0+l4*4+r][d=df*16+l15]; l lives at lane l4*4+r
  float inv[4];
#pragma unroll
  for (int r = 0; r < 4; ++r) inv[r] = 1.f / __shfl(l, l4 * 4 + r);
#pragma unroll
  for (int df = 0; df < 4; ++df)
#pragma unroll
    for (int r = 0; r < 4; ++r) {
      int row = q0 + l4 * 4 + r;
      int col = h * HDc + df * 16 + l15;
      Ob[((size_t)b * TQc + row) * Dc + col] = f2bf(accO[df][r] * inv[r]);
    }
}

// ---------------------------------------------------------------------------
extern "C" void kernel_launch(void* const* d_in, const int* in_sizes, int n_in,
                              void* d_out, int out_size, void* d_ws, size_t ws_size,
                              hipStream_t stream) {
  const float* X  = (const float*)d_in[0];
  const float* E  = (const float*)d_in[1];
  const float* Wq = (const float*)d_in[2];
  const float* bq = (const float*)d_in[3];
  const float* Wk = (const float*)d_in[4];
  const float* bk = (const float*)d_in[5];
  const float* Wv = (const float*)d_in[6];
  const float* bv = (const float*)d_in[7];
  const float* Wo = (const float*)d_in[8];
  const float* bo = (const float*)d_in[9];
  float* out = (float*)d_out;
  char* ws = (char*)d_ws;

  const size_t MB = 1ull << 20;
  if (ws_size < 58 * MB) return;  // tripwire: reproduces stub failure signature

  ushort* Xb  = (ushort*)(ws + 0 * MB);   // [4096][1024] bf16
  ushort* Eb  = (ushort*)(ws + 8 * MB);   // [4096][1024]
  ushort* Wqt = (ushort*)(ws + 16 * MB);  // [1024][1024]
  ushort* Wkt = (ushort*)(ws + 18 * MB);  // [256][1024]
  ushort* Wvt = (ushort*)(ws + 19 * MB);  // [256][1024]
  ushort* Wot = (ushort*)(ws + 20 * MB);  // [1024][1024]
  ushort* Qb  = (ushort*)(ws + 22 * MB);  // [2][16][2048][64]
  ushort* Kb  = (ushort*)(ws + 30 * MB);  // [2][4][2048][64]
  ushort* Vt  = (ushort*)(ws + 32 * MB);  // [2][4][64][2048]
  float*  qf  = (float*)(ws + 34 * MB);   // [2][2048][1024] f32 (16MB)
  ushort* Ob  = (ushort*)(ws + 34 * MB);  // aliases qf (dead after ropeq)
  float*  kf  = (float*)(ws + 50 * MB);   // [2][2048][256] f32
  float*  vf  = (float*)(ws + 54 * MB);   // [2][2048][256] f32

  // 1. casts
  cast_bf16_k<<<4096, 256, 0, stream>>>(X, Xb, (Bc * TQc * Dc) / 4);
  cast_bf16_k<<<4096, 256, 0, stream>>>(E, Eb, (Bc * TKc * Dc) / 4);
  // 2. weight transposes ([K][N] -> [N][K] bf16)
  wtrans_k<<<dim3(16, 16), 256, 0, stream>>>(Wq, Wqt, Dc, Dc);
  wtrans_k<<<dim3(4, 16), 256, 0, stream>>>(Wk, Wkt, Dc, Gc * HDc);
  wtrans_k<<<dim3(4, 16), 256, 0, stream>>>(Wv, Wvt, Dc, Gc * HDc);
  wtrans_k<<<dim3(16, 16), 256, 0, stream>>>(Wo, Wot, Dc, Dc);
  // 3. projections
  gemm_bt_bias<<<dim3(8, 32), 256, 0, stream>>>(Xb, Wqt, bq, qf, Bc * TQc, Dc, Dc);
  gemm_bt_bias<<<dim3(2, 32), 256, 0, stream>>>(Eb, Wkt, bk, kf, Bc * TKc, Gc * HDc, Dc);
  gemm_bt_bias<<<dim3(2, 32), 256, 0, stream>>>(Eb, Wvt, bv, vf, Bc * TKc, Gc * HDc, Dc);
  // 4. RoPE + repack to attention layouts
  ropeq_k<<<(Bc * Hc * TQc * 32) / 256, 256, 0, stream>>>(qf, Qb);
  ropek_k<<<(Bc * Gc * TKc * 32) / 256, 256, 0, stream>>>(kf, Kb);
  vtrans_k<<<dim3(TKc / 64, Gc, Bc), 256, 0, stream>>>(vf, Vt);
  // 5. attention  (Ob overwrites qf region — qf is dead by now)
  attn_k<<<dim3(TQc / 64, Hc, Bc), 256, 0, stream>>>(Qb, Kb, Vt, Ob);
  // 6. output projection
  gemm_bt_bias<<<dim3(8, 32), 256, 0, stream>>>(Ob, Wot, bo, out, Bc * TQc, Dc, Dc);
}

// Round 3
// 194.569 us; speedup vs baseline: 2.1464x; 2.1464x over previous
//
#include <hip/hip_runtime.h>
#include <cstdint>

// ---------------------------------------------------------------------------
// GQA cross-attention, bf16-MFMA pipeline:
//   cast -> Wt transposes -> QKV GEMMs (fp32 out) -> RoPE/repack (bf16)
//   -> flash attention (LDS-staged KV, swapped-QK^T, lane-local softmax)
//   -> output GEMM
// ---------------------------------------------------------------------------

typedef __bf16 bf16x8 __attribute__((ext_vector_type(8)));
typedef float f32x4 __attribute__((ext_vector_type(4)));

#define MFMA16(a, b, c) __builtin_amdgcn_mfma_f32_16x16x32_bf16((a), (b), (c), 0, 0, 0)

constexpr int Bc = 2, TQc = 2048, TKc = 2048, Dc = 1024, Hc = 16, Gc = 4, HDc = 64;

__device__ __forceinline__ ushort f2bf(float x) {  // RNE f32 -> bf16 bits
  uint32_t u = __builtin_bit_cast(uint32_t, x);
  u += 0x7fffu + ((u >> 16) & 1u);
  return (ushort)(u >> 16);
}

__device__ __forceinline__ void async_lds16(void* lds, const void* g) {
  // wave-uniform LDS base; lane i lands at base + 16*i (guide §5)
  __builtin_amdgcn_global_load_lds((const __attribute__((address_space(1))) uint32_t*)g,
                                   (__attribute__((address_space(3))) uint32_t*)lds,
                                   16, 0, 0);
}

// ---------------- elementwise f32 -> bf16 cast (vectorized x4) -------------
__global__ __launch_bounds__(256) void cast_bf16_k(const float* __restrict__ s,
                                                   ushort* __restrict__ d, int n4) {
  int i = blockIdx.x * 256 + threadIdx.x;
  if (i >= n4) return;
  float4 v = reinterpret_cast<const float4*>(s)[i];
  ushort4 o;
  o.x = f2bf(v.x); o.y = f2bf(v.y); o.z = f2bf(v.z); o.w = f2bf(v.w);
  reinterpret_cast<ushort4*>(d)[i] = o;
}

// ---------------- W [R][C] f32  ->  Wt [C][R] bf16 (64x64 LDS tiles) -------
__global__ __launch_bounds__(256) void wtrans_k(const float* __restrict__ src,
                                                ushort* __restrict__ dst, int R, int C) {
  __shared__ float t[64][65];
  int r0 = blockIdx.y * 64, c0 = blockIdx.x * 64;
  int tx = threadIdx.x & 63, ty = threadIdx.x >> 6;
#pragma unroll
  for (int i = 0; i < 16; ++i) {
    int r = i * 4 + ty;
    t[r][tx] = src[(size_t)(r0 + r) * C + c0 + tx];
  }
  __syncthreads();
#pragma unroll
  for (int i = 0; i < 16; ++i) {
    int c = i * 4 + ty;
    dst[(size_t)(c0 + c) * R + r0 + tx] = f2bf(t[tx][c]);
  }
}

// ------- v f32 [b][t][g*64+d] -> Vt bf16 [b][g][d][t]  (PV B-operand) ------
__global__ __launch_bounds__(256) void vtrans_k(const float* __restrict__ v,
                                                ushort* __restrict__ Vt) {
  __shared__ float t[64][65];
  int t0 = blockIdx.x * 64, g = blockIdx.y, b = blockIdx.z;
  int tx = threadIdx.x & 63, ty = threadIdx.x >> 6;
#pragma unroll
  for (int i = 0; i < 16; ++i) {
    int tl = i * 4 + ty;
    t[tl][tx] = v[((size_t)b * TKc + t0 + tl) * (Gc * HDc) + g * HDc + tx];
  }
  __syncthreads();
#pragma unroll
  for (int i = 0; i < 16; ++i) {
    int dd = i * 4 + ty;
    Vt[((size_t)(b * Gc + g) * HDc + dd) * TKc + t0 + tx] = f2bf(t[tx][dd]);
  }
}

// ------- RoPE + repack: q f32 [b][t][h*64+d] -> Qb bf16 [b][h][t][d] -------
// NOTE: folds the attention scale 1/sqrt(64)=0.125 into Q (exact in bf16).
__global__ __launch_bounds__(256) void ropeq_k(const float* __restrict__ q,
                                               ushort* __restrict__ Qb) {
  int idx = blockIdx.x * 256 + threadIdx.x;  // i(5) t(11) h(4) b(1)
  int i = idx & 31;
  int t = (idx >> 5) & (TQc - 1);
  int h = (idx >> 16) & (Hc - 1);
  int b = idx >> 20;
  float ang = (float)t * __expf(-0.28782313662425572f * (float)i);  // -ln(1e4)/32
  float sn, cs;
  __sincosf(ang, &sn, &cs);
  float2 x = *reinterpret_cast<const float2*>(&q[((size_t)b * TQc + t) * Dc + h * HDc + 2 * i]);
  ushort2 o;
  o.x = f2bf((x.x * cs - x.y * sn) * 0.125f);
  o.y = f2bf((x.x * sn + x.y * cs) * 0.125f);
  *reinterpret_cast<ushort2*>(&Qb[(((size_t)(b * Hc + h)) * TQc + t) * HDc + 2 * i]) = o;
}

__global__ __launch_bounds__(256) void ropek_k(const float* __restrict__ k,
                                               ushort* __restrict__ Kb) {
  int idx = blockIdx.x * 256 + threadIdx.x;  // i(5) t(11) g(2) b(1)
  int i = idx & 31;
  int t = (idx >> 5) & (TKc - 1);
  int g = (idx >> 16) & (Gc - 1);
  int b = idx >> 18;
  float ang = (float)t * __expf(-0.28782313662425572f * (float)i);
  float sn, cs;
  __sincosf(ang, &sn, &cs);
  float2 x = *reinterpret_cast<const float2*>(&k[((size_t)b * TKc + t) * (Gc * HDc) + g * HDc + 2 * i]);
  ushort2 o;
  o.x = f2bf(x.x * cs - x.y * sn);
  o.y = f2bf(x.x * sn + x.y * cs);
  *reinterpret_cast<ushort2*>(&Kb[(((size_t)(b * Gc + g)) * TKc + t) * HDc + 2 * i]) = o;
}

// ------- C[M][N] f32 = A[M][K]bf16 * Bt[N][K]bf16^T + bias[N] --------------
// 128x128 tile, BK=32, 4 waves (2x2), global_load_lds width-16 staging.
__global__ __launch_bounds__(256) void gemm_bt_bias(const ushort* __restrict__ A,
                                                    const ushort* __restrict__ Bt,
                                                    const float* __restrict__ bias,
                                                    float* __restrict__ C,
                                                    int M, int N, int K) {
  __shared__ __attribute__((aligned(16))) ushort sA[128 * 32];
  __shared__ __attribute__((aligned(16))) ushort sB[128 * 32];
  const int tid = threadIdx.x;
  const int lane = tid & 63, wid = tid >> 6;
  const int l15 = lane & 15, l4 = lane >> 4;
  const int m0 = blockIdx.y * 128, n0 = blockIdx.x * 128;
  const int wr = (wid >> 1) * 64, wc = (wid & 1) * 64;

  const f32x4 z = {0.f, 0.f, 0.f, 0.f};
  f32x4 acc[4][4];
#pragma unroll
  for (int mi = 0; mi < 4; ++mi)
#pragma unroll
    for (int ni = 0; ni < 4; ++ni) acc[mi][ni] = z;

  for (int k0 = 0; k0 < K; k0 += 32) {
#pragma unroll
    for (int i = 0; i < 2; ++i) {
      int c = wid * 2 + i;            // 1KB chunk index (8 per tile)
      int tb = c * 1024 + lane * 16;  // byte within tile; 64B per row (BK*2)
      int row = tb >> 6;
      int cole = (tb & 63) >> 1;
      async_lds16((char*)sA + c * 1024, A + (size_t)(m0 + row) * K + k0 + cole);
      async_lds16((char*)sB + c * 1024, Bt + (size_t)(n0 + row) * K + k0 + cole);
    }
    __syncthreads();
    bf16x8 af[4], bfr[4];
#pragma unroll
    for (int mi = 0; mi < 4; ++mi)
      af[mi] = *reinterpret_cast<const bf16x8*>(&sA[(wr + mi * 16 + l15) * 32 + l4 * 8]);
#pragma unroll
    for (int ni = 0; ni < 4; ++ni)
      bfr[ni] = *reinterpret_cast<const bf16x8*>(&sB[(wc + ni * 16 + l15) * 32 + l4 * 8]);
#pragma unroll
    for (int mi = 0; mi < 4; ++mi)
#pragma unroll
      for (int ni = 0; ni < 4; ++ni)
        acc[mi][ni] = MFMA16(af[mi], bfr[ni], acc[mi][ni]);
    __syncthreads();
  }

#pragma unroll
  for (int mi = 0; mi < 4; ++mi)
#pragma unroll
    for (int ni = 0; ni < 4; ++ni) {
      int col = n0 + wc + ni * 16 + l15;
      float bv = bias[col];
      int rowb = m0 + wr + mi * 16 + l4 * 4;  // D: row=(l>>4)*4+r, col=l&15
#pragma unroll
      for (int r = 0; r < 4; ++r)
        C[(size_t)(rowb + r) * N + col] = acc[mi][ni][r] + bv;
    }
}

// ------- flash attention, LDS-staged K/V, swapped-QK^T ---------------------
// Qb[b][h][t][64] (pre-scaled), Kb[b][g][t][64], Vt[b][g][64][t].
// 512 thr = 8 waves, QBLK=128 (16 q-rows/wave), KVBLK=64, double-buffered LDS.
// K/V tiles: 64 rows x 128B, XOR-swizzled (chunk ^= row&7): linear LDS dest,
// pre-swizzled per-lane GLOBAL source, swizzled ds_read (rule #21).
__global__ __launch_bounds__(512, 4) void attn_k(const ushort* __restrict__ Qg,
                                                 const ushort* __restrict__ Kg,
                                                 const ushort* __restrict__ Vg,
                                                 ushort* __restrict__ Ob) {
  __shared__ __attribute__((aligned(16))) char smem[48 * 1024];
  const int lane = threadIdx.x & 63, wid = threadIdx.x >> 6;
  const int l15 = lane & 15, l4 = lane >> 4;
  // XCD-aware decode: bid&7 = (b,g) group -> each XCD L2 caches ONE group's K/V
  const int bid = blockIdx.x;  // 512 blocks
  const int bg = bid & 7, pos = bid >> 3;
  const int b = bg >> 2, g = bg & 3;
  const int h = g * 4 + (pos >> 4);
  const int q0 = (pos & 15) * 128 + wid * 16;
  const ushort* Qp = Qg + ((size_t)(b * Hc + h)) * TQc * HDc;
  const ushort* Kp = Kg + ((size_t)(b * Gc + g)) * TKc * HDc;
  const ushort* Vp = Vg + ((size_t)(b * Gc + g)) * HDc * TKc;
  char* sK = smem;                         // [2][8192]
  char* sV = smem + 16384;                 // [2][8192]
  char* pb = smem + 32768 + wid * 2048;    // per-wave P tile [16][64] bf16
  const int rx = (l15 & 7) << 4;           // P-row swizzle
  const int swz = l15 & 7;                 // K/V fragment chunk swizzle

  // staging geometry: wave stages 1KB of K and 1KB of V per tile
  const int sr = wid * 8 + (lane >> 3);              // tile row this lane fills
  const int sc = (lane & 7) ^ ((lane >> 3) & 7);     // pre-swizzled src chunk
  const char* Kb8 = (const char*)Kp;
  const char* Vb8 = (const char*)Vp;

  // Q (B operand): col n=l15 -> q=q0+l15, k=l4*8+j -> d
  bf16x8 bq0 = *reinterpret_cast<const bf16x8*>(Qp + (size_t)(q0 + l15) * HDc + l4 * 8);
  bf16x8 bq1 = *reinterpret_cast<const bf16x8*>(Qp + (size_t)(q0 + l15) * HDc + 32 + l4 * 8);

  float m = -INFINITY, l = 0.f;
  const f32x4 z = {0.f, 0.f, 0.f, 0.f};
  f32x4 accO[4] = {z, z, z, z};

  constexpr int NT = TKc / 64;
  // prologue: stage tile 0 into buffer 0
  async_lds16(sK + wid * 1024, Kb8 + (size_t)sr * 128 + sc * 16);
  async_lds16(sV + wid * 1024, Vb8 + (size_t)sr * (TKc * 2) + sc * 16);
  __syncthreads();

  int buf = 0;
  for (int kt = 0; kt < NT; ++kt) {
    if (kt + 1 < NT) {  // issue next-tile loads; they complete under compute
      char* dK = sK + (buf ^ 1) * 8192 + wid * 1024;
      char* dV = sV + (buf ^ 1) * 8192 + wid * 1024;
      async_lds16(dK, Kb8 + ((size_t)(kt + 1) * 64 + sr) * 128 + sc * 16);
      async_lds16(dV, Vb8 + (size_t)sr * (TKc * 2) + (size_t)(kt + 1) * 128 + sc * 16);
    }
    const char* sKb = sK + buf * 8192;
    const char* sVb = sV + buf * 8192;

    // QK^T: A = K[key=nf*16+l15][d], B = Q -> S^T[key][q=l15]
    f32x4 s[4] = {z, z, z, z};
#pragma unroll
    for (int nf = 0; nf < 4; ++nf) {
      const char* krow = sKb + (nf * 16 + l15) * 128;
      bf16x8 k0 = *reinterpret_cast<const bf16x8*>(krow + ((l4 ^ swz) * 16));
      bf16x8 k1 = *reinterpret_cast<const bf16x8*>(krow + (((4 + l4) ^ swz) * 16));
      s[nf] = MFMA16(k0, bq0, s[nf]);
      s[nf] = MFMA16(k1, bq1, s[nf]);
    }
    // V fragments from LDS: B[k=key][n=d]:  va[df][kk] = V^T tile row d
    bf16x8 va[4][2];
#pragma unroll
    for (int df = 0; df < 4; ++df) {
      const char* vrow = sVb + (df * 16 + l15) * 128;
#pragma unroll
      for (int kk = 0; kk < 2; ++kk)
        va[df][kk] = *reinterpret_cast<const bf16x8*>(vrow + (((kk * 4 + l4) ^ swz) * 16));
    }

    // ---- lane-local softmax (one q-row per lane) ----
    float pm = fmaxf(fmaxf(fmaxf(s[0][0], s[0][1]), fmaxf(s[0][2], s[0][3])),
                     fmaxf(fmaxf(s[1][0], s[1][1]), fmaxf(s[1][2], s[1][3])));
    pm = fmaxf(pm, fmaxf(fmaxf(fmaxf(s[2][0], s[2][1]), fmaxf(s[2][2], s[2][3])),
                         fmaxf(fmaxf(s[3][0], s[3][1]), fmaxf(s[3][2], s[3][3]))));
    pm = fmaxf(pm, __shfl_xor(pm, 16));
    pm = fmaxf(pm, __shfl_xor(pm, 32));
    if (!__all(pm - m <= 8.f)) {  // T13 defer-max
      float mn = fmaxf(m, pm);
      float sc2 = __expf(m - mn);
      m = mn;
      l *= sc2;
#pragma unroll
      for (int df = 0; df < 4; ++df) accO[df] *= sc2;
    }
    float ps = 0.f;
#pragma unroll
    for (int nf = 0; nf < 4; ++nf)
#pragma unroll
      for (int r = 0; r < 4; ++r) {
        float p = __expf(s[nf][r] - m);
        s[nf][r] = p;
        ps += p;
      }
    ps += __shfl_xor(ps, 16);
    ps += __shfl_xor(ps, 32);
    l += ps;

    // ---- P -> per-wave LDS (row q=l15): 4x ds_write_b64, swizzled ----
#pragma unroll
    for (int nf = 0; nf < 4; ++nf) {
      uint2 w;
      w.x = (uint)f2bf(s[nf][0]) | ((uint)f2bf(s[nf][1]) << 16);
      w.y = (uint)f2bf(s[nf][2]) | ((uint)f2bf(s[nf][3]) << 16);
      *reinterpret_cast<uint2*>(pb + l15 * 128 + ((nf * 32 + l4 * 8) ^ rx)) = w;
    }
    // ---- PV: A = P[q=l15][k=key], B = V^T[key][d] ----
    bf16x8 ap0 = *reinterpret_cast<const bf16x8*>(pb + l15 * 128 + ((l4 * 16) ^ rx));
    bf16x8 ap1 = *reinterpret_cast<const bf16x8*>(pb + l15 * 128 + ((64 + l4 * 16) ^ rx));
#pragma unroll
    for (int df = 0; df < 4; ++df)
      accO[df] = MFMA16(ap1, va[df][1], MFMA16(ap0, va[df][0], accO[df]));

    __syncthreads();  // drains vmcnt(0): next tile landed; all waves done reading
    buf ^= 1;
  }

  // epilogue: lane holds O[q=q0+l4*4+r][d=df*16+l15]; l lives at lane l4*4+r
  float inv[4];
#pragma unroll
  for (int r = 0; r < 4; ++r) inv[r] = 1.f / __shfl(l, l4 * 4 + r);
#pragma unroll
  for (int df = 0; df < 4; ++df)
#pragma unroll
    for (int r = 0; r < 4; ++r) {
      int row = q0 + l4 * 4 + r;
      int col = h * HDc + df * 16 + l15;
      Ob[((size_t)b * TQc + row) * Dc + col] = f2bf(accO[df][r] * inv[r]);
    }
}

// ---------------------------------------------------------------------------
extern "C" void kernel_launch(void* const* d_in, const int* in_sizes, int n_in,
                              void* d_out, int out_size, void* d_ws, size_t ws_size,
                              hipStream_t stream) {
  const float* X  = (const float*)d_in[0];
  const float* E  = (const float*)d_in[1];
  const float* Wq = (const float*)d_in[2];
  const float* bq = (const float*)d_in[3];
  const float* Wk = (const float*)d_in[4];
  const float* bk = (const float*)d_in[5];
  const float* Wv = (const float*)d_in[6];
  const float* bv = (const float*)d_in[7];
  const float* Wo = (const float*)d_in[8];
  const float* bo = (const float*)d_in[9];
  float* out = (float*)d_out;
  char* ws = (char*)d_ws;

  const size_t MB = 1ull << 20;
  if (ws_size < 58 * MB) return;  // tripwire: reproduces stub failure signature

  ushort* Xb  = (ushort*)(ws + 0 * MB);   // [4096][1024] bf16
  ushort* Eb  = (ushort*)(ws + 8 * MB);   // [4096][1024]
  ushort* Wqt = (ushort*)(ws + 16 * MB);  // [1024][1024]
  ushort* Wkt = (ushort*)(ws + 18 * MB);  // [256][1024]
  ushort* Wvt = (ushort*)(ws + 19 * MB);  // [256][1024]
  ushort* Wot = (ushort*)(ws + 20 * MB);  // [1024][1024]
  ushort* Qb  = (ushort*)(ws + 22 * MB);  // [2][16][2048][64]
  ushort* Kb  = (ushort*)(ws + 30 * MB);  // [2][4][2048][64]
  ushort* Vt  = (ushort*)(ws + 32 * MB);  // [2][4][64][2048]
  float*  qf  = (float*)(ws + 34 * MB);   // [2][2048][1024] f32 (16MB)
  ushort* Ob  = (ushort*)(ws + 34 * MB);  // aliases qf (dead after ropeq)
  float*  kf  = (float*)(ws + 50 * MB);   // [2][2048][256] f32
  float*  vf  = (float*)(ws + 54 * MB);   // [2][2048][256] f32

  // 1. casts
  cast_bf16_k<<<4096, 256, 0, stream>>>(X, Xb, (Bc * TQc * Dc) / 4);
  cast_bf16_k<<<4096, 256, 0, stream>>>(E, Eb, (Bc * TKc * Dc) / 4);
  // 2. weight transposes ([K][N] -> [N][K] bf16)
  wtrans_k<<<dim3(16, 16), 256, 0, stream>>>(Wq, Wqt, Dc, Dc);
  wtrans_k<<<dim3(4, 16), 256, 0, stream>>>(Wk, Wkt, Dc, Gc * HDc);
  wtrans_k<<<dim3(4, 16), 256, 0, stream>>>(Wv, Wvt, Dc, Gc * HDc);
  wtrans_k<<<dim3(16, 16), 256, 0, stream>>>(Wo, Wot, Dc, Dc);
  // 3. projections
  gemm_bt_bias<<<dim3(8, 32), 256, 0, stream>>>(Xb, Wqt, bq, qf, Bc * TQc, Dc, Dc);
  gemm_bt_bias<<<dim3(2, 32), 256, 0, stream>>>(Eb, Wkt, bk, kf, Bc * TKc, Gc * HDc, Dc);
  gemm_bt_bias<<<dim3(2, 32), 256, 0, stream>>>(Eb, Wvt, bv, vf, Bc * TKc, Gc * HDc, Dc);
  // 4. RoPE + repack to attention layouts
  ropeq_k<<<(Bc * Hc * TQc * 32) / 256, 256, 0, stream>>>(qf, Qb);
  ropek_k<<<(Bc * Gc * TKc * 32) / 256, 256, 0, stream>>>(kf, Kb);
  vtrans_k<<<dim3(TKc / 64, Gc, Bc), 256, 0, stream>>>(vf, Vt);
  // 5. attention  (Ob overwrites qf region — qf is dead by now)
  attn_k<<<dim3(512), dim3(512), 0, stream>>>(Qb, Kb, Vt, Ob);
  // 6. output projection
  gemm_bt_bias<<<dim3(8, 32), 256, 0, stream>>>(Ob, Wot, bo, out, Bc * TQc, Dc, Dc);
}

// Round 4
// 135.830 us; speedup vs baseline: 3.0746x; 1.4324x over previous
//
#include <hip/hip_runtime.h>
#include <cstdint>

// ---------------------------------------------------------------------------
// GQA cross-attention, bf16-MFMA pipeline (6 dispatches):
//   cast2 (X,E -> bf16) -> wtrans_all (Wq,Wo,Wk|Wv -> bf16 ^T)
//   -> gemm64<1> (Q-proj + RoPE + scale -> Qb)
//   -> gemm64<2> (KV-proj; K+RoPE -> Kb, V -> transposed Vt)
//   -> attn_k (LDS-staged flash attention) -> gemm64<0> (O-proj, f32 out)
// ---------------------------------------------------------------------------

typedef __bf16 bf16x8 __attribute__((ext_vector_type(8)));
typedef __bf16 bf16x4v __attribute__((ext_vector_type(4)));
typedef float f32x4 __attribute__((ext_vector_type(4)));

#define MFMA16(a, b, c) __builtin_amdgcn_mfma_f32_16x16x32_bf16((a), (b), (c), 0, 0, 0)

constexpr int Bc = 2, TQc = 2048, TKc = 2048, Dc = 1024, Hc = 16, Gc = 4, HDc = 64;

__device__ __forceinline__ ushort bfbits(float x) {  // native RNE f32->bf16
  __bf16 h = (__bf16)x;
  return __builtin_bit_cast(ushort, h);
}

__device__ __forceinline__ void async_lds16(void* lds, const void* g) {
  // wave-uniform LDS base; lane i lands at base + 16*i (guide §5)
  __builtin_amdgcn_global_load_lds((const __attribute__((address_space(1))) uint32_t*)g,
                                   (__attribute__((address_space(3))) uint32_t*)lds,
                                   16, 0, 0);
}

// ---------------- f32 -> bf16 cast, X and E in one launch ------------------
__global__ __launch_bounds__(256) void cast2_k(const float* __restrict__ X,
                                               const float* __restrict__ E,
                                               ushort* __restrict__ Xb,
                                               ushort* __restrict__ Eb) {
  int i = blockIdx.x * 256 + threadIdx.x;  // 1M float4 per input
  const float* s = blockIdx.y ? E : X;
  ushort* d = blockIdx.y ? Eb : Xb;
  float4 v = reinterpret_cast<const float4*>(s)[i];
  ushort4 o;
  o.x = bfbits(v.x); o.y = bfbits(v.y); o.z = bfbits(v.z); o.w = bfbits(v.w);
  reinterpret_cast<ushort4*>(d)[i] = o;
}

// ------- all weight transposes: W[R][C] f32 -> Wt[C][R] bf16 ---------------
// z=0: Wq -> Wqt; z=1: Wo -> Wot; z=2: Wk -> Wkvt[0:256], Wv -> Wkvt[256:512]
__global__ __launch_bounds__(256) void wtrans_all(const float* __restrict__ Wq,
                                                  const float* __restrict__ Wo,
                                                  const float* __restrict__ Wk,
                                                  const float* __restrict__ Wv,
                                                  ushort* __restrict__ Wqt,
                                                  ushort* __restrict__ Wot,
                                                  ushort* __restrict__ Wkvt) {
  __shared__ float t[64][65];
  const int z = blockIdx.z;
  const float* src;
  ushort* dst;
  int C, c0;
  if (z == 0)      { src = Wq; dst = Wqt; C = 1024; c0 = blockIdx.x * 64; }
  else if (z == 1) { src = Wo; dst = Wot; C = 1024; c0 = blockIdx.x * 64; }
  else {
    if (blockIdx.x >= 8) return;
    if (blockIdx.x < 4) { src = Wk; dst = Wkvt; }
    else                { src = Wv; dst = Wkvt + 256 * 1024; }
    C = 256; c0 = (blockIdx.x & 3) * 64;
  }
  const int r0 = blockIdx.y * 64;
  const int tx = threadIdx.x & 63, ty = threadIdx.x >> 6;
#pragma unroll
  for (int i = 0; i < 16; ++i) {
    int r = i * 4 + ty;
    t[r][tx] = src[(size_t)(r0 + r) * C + c0 + tx];
  }
  __syncthreads();
#pragma unroll
  for (int i = 0; i < 16; ++i) {
    int c = i * 4 + ty;
    dst[(size_t)(c0 + c) * 1024 + r0 + tx] = bfbits(t[tx][c]);
  }
}

// ------- GEMM 128x64 tile, BK=32, 4 waves (2Mx2N), fused epilogues ---------
// EPI=0: Cf = A*Bt^T + bias0 (f32)
// EPI=1: Q-proj -> RoPE -> *0.125 -> Qb[b][h][t][64] bf16
// EPI=2: KV-proj (N=512): col<256 K+RoPE -> Kb[b][g][t][64];
//                         col>=256 V -> Vt[b][g][64][t]
template <int EPI>
__global__ __launch_bounds__(256) void gemm64(const ushort* __restrict__ A,
                                              const ushort* __restrict__ Bt,
                                              const float* __restrict__ bias0,
                                              const float* __restrict__ bias1,
                                              float* __restrict__ Cf,
                                              ushort* __restrict__ U0,
                                              ushort* __restrict__ U1,
                                              int N, int K) {
  __shared__ __attribute__((aligned(16))) ushort sA[128 * 32];
  __shared__ __attribute__((aligned(16))) ushort sB[64 * 32];
  const int lane = threadIdx.x & 63, wid = threadIdx.x >> 6;
  const int l15 = lane & 15, l4 = lane >> 4;
  const int m0 = blockIdx.y * 128, n0 = blockIdx.x * 64;
  const int wr = (wid >> 1) * 64, wc = (wid & 1) * 32;
  const int srow = lane >> 2;        // 16 rows per 1KB chunk
  const int scol = (lane & 3) * 8;   // ushort offset within row

  const f32x4 z = {0.f, 0.f, 0.f, 0.f};
  f32x4 acc[4][2];
#pragma unroll
  for (int mi = 0; mi < 4; ++mi)
#pragma unroll
    for (int ni = 0; ni < 2; ++ni) acc[mi][ni] = z;

  for (int k0 = 0; k0 < K; k0 += 32) {
#pragma unroll
    for (int i = 0; i < 2; ++i) {
      int c = wid * 2 + i;  // A chunk (8 x 1KB)
      async_lds16((char*)sA + c * 1024, A + (size_t)(m0 + c * 16 + srow) * K + k0 + scol);
    }
    async_lds16((char*)sB + wid * 1024, Bt + (size_t)(n0 + wid * 16 + srow) * K + k0 + scol);
    __syncthreads();
    bf16x8 af[4], bfr[2];
#pragma unroll
    for (int mi = 0; mi < 4; ++mi)
      af[mi] = *reinterpret_cast<const bf16x8*>(&sA[(wr + mi * 16 + l15) * 32 + l4 * 8]);
#pragma unroll
    for (int ni = 0; ni < 2; ++ni)
      bfr[ni] = *reinterpret_cast<const bf16x8*>(&sB[(wc + ni * 16 + l15) * 32 + l4 * 8]);
#pragma unroll
    for (int mi = 0; mi < 4; ++mi)
#pragma unroll
      for (int ni = 0; ni < 2; ++ni)
        acc[mi][ni] = MFMA16(af[mi], bfr[ni], acc[mi][ni]);
    __syncthreads();
  }

  // ---- epilogues.  D-frag: row = rowb + r, col = n0+wc+ni*16+l15 ----
#pragma unroll
  for (int ni = 0; ni < 2; ++ni) {
    const int col = n0 + wc + ni * 16 + l15;
    if constexpr (EPI == 0) {
      const float bv = bias0[col];
#pragma unroll
      for (int mi = 0; mi < 4; ++mi) {
        const int rowb = m0 + wr + mi * 16 + l4 * 4;
#pragma unroll
        for (int r = 0; r < 4; ++r)
          Cf[(size_t)(rowb + r) * N + col] = acc[mi][ni][r] + bv;
      }
    } else if constexpr (EPI == 1) {
      const int h = col >> 6, d = col & 63, fi = d >> 1, odd = d & 1;
      const float div = __expf(-0.28782313662425572f * (float)fi);  // -ln(1e4)/32
      const float bv = bias0[col];
#pragma unroll
      for (int mi = 0; mi < 4; ++mi) {
        const int rowb = m0 + wr + mi * 16 + l4 * 4;
#pragma unroll
        for (int r = 0; r < 4; ++r) {
          const int row = rowb + r, b = row >> 11, t = row & 2047;
          const float val = acc[mi][ni][r] + bv;
          const float prt = __shfl_xor(val, 1);  // partner column (d^1)
          float sn, cs;
          __sincosf((float)t * div, &sn, &cs);
          const float o = odd ? (prt * sn + val * cs) : (val * cs - prt * sn);
          U0[(((size_t)(b * Hc + h)) * TQc + t) * HDc + d] = bfbits(o * 0.125f);
        }
      }
    } else {  // EPI == 2
      if (col < 256) {  // K path: RoPE -> Kb[b][g][t][d]
        const int g = col >> 6, d = col & 63, fi = d >> 1, odd = d & 1;
        const float div = __expf(-0.28782313662425572f * (float)fi);
        const float bv = bias0[col];
#pragma unroll
        for (int mi = 0; mi < 4; ++mi) {
          const int rowb = m0 + wr + mi * 16 + l4 * 4;
#pragma unroll
          for (int r = 0; r < 4; ++r) {
            const int row = rowb + r, b = row >> 11, t = row & 2047;
            const float val = acc[mi][ni][r] + bv;
            const float prt = __shfl_xor(val, 1);
            float sn, cs;
            __sincosf((float)t * div, &sn, &cs);
            const float o = odd ? (prt * sn + val * cs) : (val * cs - prt * sn);
            U0[(((size_t)(b * Gc + g)) * TKc + t) * HDc + d] = bfbits(o);
          }
        }
      } else {  // V path: transpose-write Vt[b][g][d][t] (8B packed stores)
        const int c2 = col - 256;
        const int g = c2 >> 6, d = c2 & 63;
        const float bv = bias1[c2];
#pragma unroll
        for (int mi = 0; mi < 4; ++mi) {
          const int rowb = m0 + wr + mi * 16 + l4 * 4;
          const int b = rowb >> 11, t0 = rowb & 2047;
          ushort4 w;
          w.x = bfbits(acc[mi][ni][0] + bv);
          w.y = bfbits(acc[mi][ni][1] + bv);
          w.z = bfbits(acc[mi][ni][2] + bv);
          w.w = bfbits(acc[mi][ni][3] + bv);
          *reinterpret_cast<ushort4*>(
              &U1[(((size_t)(b * Gc + g)) * HDc + d) * TKc + t0]) = w;
        }
      }
    }
  }
}

// ------- flash attention, LDS-staged K/V, swapped-QK^T ---------------------
// Qb[b][h][t][64] (pre-scaled), Kb[b][g][t][64], Vt[b][g][64][t].
// 512 thr = 8 waves, QBLK=128 (16 q-rows/wave), KVBLK=64, double-buffered LDS.
// K/V tiles: 64 rows x 128B, XOR-swizzled (chunk ^= row&7): linear LDS dest,
// pre-swizzled per-lane GLOBAL source, swizzled ds_read (rule #21).
__global__ __launch_bounds__(512, 4) void attn_k(const ushort* __restrict__ Qg,
                                                 const ushort* __restrict__ Kg,
                                                 const ushort* __restrict__ Vg,
                                                 ushort* __restrict__ Ob) {
  __shared__ __attribute__((aligned(16))) char smem[48 * 1024];
  const int lane = threadIdx.x & 63, wid = threadIdx.x >> 6;
  const int l15 = lane & 15, l4 = lane >> 4;
  // XCD-aware decode: bid&7 = (b,g) group -> each XCD L2 caches ONE group's K/V
  const int bid = blockIdx.x;  // 512 blocks
  const int bg = bid & 7, pos = bid >> 3;
  const int b = bg >> 2, g = bg & 3;
  const int h = g * 4 + (pos >> 4);
  const int q0 = (pos & 15) * 128 + wid * 16;
  const ushort* Qp = Qg + ((size_t)(b * Hc + h)) * TQc * HDc;
  const ushort* Kp = Kg + ((size_t)(b * Gc + g)) * TKc * HDc;
  const ushort* Vp = Vg + ((size_t)(b * Gc + g)) * HDc * TKc;
  char* sK = smem;                         // [2][8192]
  char* sV = smem + 16384;                 // [2][8192]
  char* pb = smem + 32768 + wid * 2048;    // per-wave P tile [16][64] bf16
  const int rx = (l15 & 7) << 4;           // P-row swizzle
  const int swz = l15 & 7;                 // K/V fragment chunk swizzle

  // staging geometry: wave stages 1KB of K and 1KB of V per tile
  const int sr = wid * 8 + (lane >> 3);              // tile row this lane fills
  const int sc = (lane & 7) ^ ((lane >> 3) & 7);     // pre-swizzled src chunk
  const char* Kb8 = (const char*)Kp;
  const char* Vb8 = (const char*)Vp;

  // Q (B operand): col n=l15 -> q=q0+l15, k=l4*8+j -> d
  bf16x8 bq0 = *reinterpret_cast<const bf16x8*>(Qp + (size_t)(q0 + l15) * HDc + l4 * 8);
  bf16x8 bq1 = *reinterpret_cast<const bf16x8*>(Qp + (size_t)(q0 + l15) * HDc + 32 + l4 * 8);

  float m = -INFINITY, l = 0.f;
  const f32x4 z = {0.f, 0.f, 0.f, 0.f};
  f32x4 accO[4] = {z, z, z, z};

  constexpr int NT = TKc / 64;
  // prologue: stage tile 0 into buffer 0
  async_lds16(sK + wid * 1024, Kb8 + (size_t)sr * 128 + sc * 16);
  async_lds16(sV + wid * 1024, Vb8 + (size_t)sr * (TKc * 2) + sc * 16);
  __syncthreads();

  int buf = 0;
  for (int kt = 0; kt < NT; ++kt) {
    if (kt + 1 < NT) {  // issue next-tile loads; they complete under compute
      char* dK = sK + (buf ^ 1) * 8192 + wid * 1024;
      char* dV = sV + (buf ^ 1) * 8192 + wid * 1024;
      async_lds16(dK, Kb8 + ((size_t)(kt + 1) * 64 + sr) * 128 + sc * 16);
      async_lds16(dV, Vb8 + (size_t)sr * (TKc * 2) + (size_t)(kt + 1) * 128 + sc * 16);
    }
    const char* sKb = sK + buf * 8192;
    const char* sVb = sV + buf * 8192;

    // QK^T: A = K[key=nf*16+l15][d], B = Q -> S^T[key][q=l15]
    f32x4 s[4] = {z, z, z, z};
#pragma unroll
    for (int nf = 0; nf < 4; ++nf) {
      const char* krow = sKb + (nf * 16 + l15) * 128;
      bf16x8 k0 = *reinterpret_cast<const bf16x8*>(krow + ((l4 ^ swz) * 16));
      bf16x8 k1 = *reinterpret_cast<const bf16x8*>(krow + (((4 + l4) ^ swz) * 16));
      s[nf] = MFMA16(k0, bq0, s[nf]);
      s[nf] = MFMA16(k1, bq1, s[nf]);
    }
    // V fragments from LDS: B[k=key][n=d]:  va[df][kk] = V^T tile row d
    bf16x8 va[4][2];
#pragma unroll
    for (int df = 0; df < 4; ++df) {
      const char* vrow = sVb + (df * 16 + l15) * 128;
#pragma unroll
      for (int kk = 0; kk < 2; ++kk)
        va[df][kk] = *reinterpret_cast<const bf16x8*>(vrow + (((kk * 4 + l4) ^ swz) * 16));
    }

    // ---- lane-local softmax (one q-row per lane) ----
    float pm = fmaxf(fmaxf(fmaxf(s[0][0], s[0][1]), fmaxf(s[0][2], s[0][3])),
                     fmaxf(fmaxf(s[1][0], s[1][1]), fmaxf(s[1][2], s[1][3])));
    pm = fmaxf(pm, fmaxf(fmaxf(fmaxf(s[2][0], s[2][1]), fmaxf(s[2][2], s[2][3])),
                         fmaxf(fmaxf(s[3][0], s[3][1]), fmaxf(s[3][2], s[3][3]))));
    pm = fmaxf(pm, __shfl_xor(pm, 16));
    pm = fmaxf(pm, __shfl_xor(pm, 32));
    if (!__all(pm - m <= 8.f)) {  // T13 defer-max
      float mn = fmaxf(m, pm);
      float sc2 = __expf(m - mn);
      m = mn;
      l *= sc2;
#pragma unroll
      for (int df = 0; df < 4; ++df) accO[df] *= sc2;
    }
    float ps = 0.f;
#pragma unroll
    for (int nf = 0; nf < 4; ++nf)
#pragma unroll
      for (int r = 0; r < 4; ++r) {
        float p = __expf(s[nf][r] - m);
        s[nf][r] = p;
        ps += p;
      }
    ps += __shfl_xor(ps, 16);
    ps += __shfl_xor(ps, 32);
    l += ps;

    // ---- P -> per-wave LDS (row q=l15): 4x ds_write_b64, swizzled ----
#pragma unroll
    for (int nf = 0; nf < 4; ++nf) {
      bf16x4v pv;
      pv[0] = (__bf16)s[nf][0];
      pv[1] = (__bf16)s[nf][1];
      pv[2] = (__bf16)s[nf][2];
      pv[3] = (__bf16)s[nf][3];
      *reinterpret_cast<uint2*>(pb + l15 * 128 + ((nf * 32 + l4 * 8) ^ rx)) =
          __builtin_bit_cast(uint2, pv);
    }
    // ---- PV: A = P[q=l15][k=key], B = V^T[key][d] ----
    bf16x8 ap0 = *reinterpret_cast<const bf16x8*>(pb + l15 * 128 + ((l4 * 16) ^ rx));
    bf16x8 ap1 = *reinterpret_cast<const bf16x8*>(pb + l15 * 128 + ((64 + l4 * 16) ^ rx));
#pragma unroll
    for (int df = 0; df < 4; ++df)
      accO[df] = MFMA16(ap1, va[df][1], MFMA16(ap0, va[df][0], accO[df]));

    __syncthreads();  // drains vmcnt(0): next tile landed; all waves done reading
    buf ^= 1;
  }

  // epilogue: lane holds O[q=q0+l4*4+r][d=df*16+l15]; l lives at lane l4*4+r
  float inv[4];
#pragma unroll
  for (int r = 0; r < 4; ++r) inv[r] = 1.f / __shfl(l, l4 * 4 + r);
#pragma unroll
  for (int df = 0; df < 4; ++df)
#pragma unroll
    for (int r = 0; r < 4; ++r) {
      int row = q0 + l4 * 4 + r;
      int col = h * HDc + df * 16 + l15;
      Ob[((size_t)b * TQc + row) * Dc + col] = bfbits(accO[df][r] * inv[r]);
    }
}

// ---------------------------------------------------------------------------
extern "C" void kernel_launch(void* const* d_in, const int* in_sizes, int n_in,
                              void* d_out, int out_size, void* d_ws, size_t ws_size,
                              hipStream_t stream) {
  const float* X  = (const float*)d_in[0];
  const float* E  = (const float*)d_in[1];
  const float* Wq = (const float*)d_in[2];
  const float* bq = (const float*)d_in[3];
  const float* Wk = (const float*)d_in[4];
  const float* bk = (const float*)d_in[5];
  const float* Wv = (const float*)d_in[6];
  const float* bv = (const float*)d_in[7];
  const float* Wo = (const float*)d_in[8];
  const float* bo = (const float*)d_in[9];
  float* out = (float*)d_out;
  char* ws = (char*)d_ws;

  const size_t MB = 1ull << 20;
  if (ws_size < 42 * MB) return;  // tripwire: reproduces stub failure signature

  ushort* Xb   = (ushort*)(ws + 0 * MB);   // [4096][1024] bf16
  ushort* Eb   = (ushort*)(ws + 8 * MB);   // [4096][1024]
  ushort* Wqt  = (ushort*)(ws + 16 * MB);  // [1024][1024]
  ushort* Wkvt = (ushort*)(ws + 18 * MB);  // [512][1024] (Wk^T | Wv^T)
  ushort* Wot  = (ushort*)(ws + 19 * MB);  // [1024][1024]
  ushort* Qb   = (ushort*)(ws + 21 * MB);  // [2][16][2048][64]
  ushort* Kb   = (ushort*)(ws + 29 * MB);  // [2][4][2048][64]
  ushort* Vt   = (ushort*)(ws + 31 * MB);  // [2][4][64][2048]
  ushort* Ob   = (ushort*)(ws + 33 * MB);  // [2][2048][1024]

  // 1. casts (X, E)
  cast2_k<<<dim3(4096, 2), 256, 0, stream>>>(X, E, Xb, Eb);
  // 2. all weight transposes
  wtrans_all<<<dim3(16, 16, 3), 256, 0, stream>>>(Wq, Wo, Wk, Wv, Wqt, Wot, Wkvt);
  // 3. Q projection + RoPE + scale -> Qb
  gemm64<1><<<dim3(16, 32), 256, 0, stream>>>(Xb, Wqt, bq, nullptr, nullptr,
                                              Qb, nullptr, Dc, Dc);
  // 4. KV projection: K+RoPE -> Kb, V -> Vt
  gemm64<2><<<dim3(8, 32), 256, 0, stream>>>(Eb, Wkvt, bk, bv, nullptr,
                                             Kb, Vt, 2 * Gc * HDc, Dc);
  // 5. attention -> Ob
  attn_k<<<dim3(512), dim3(512), 0, stream>>>(Qb, Kb, Vt, Ob);
  // 6. output projection -> out (f32)
  gemm64<0><<<dim3(16, 32), 256, 0, stream>>>(Ob, Wot, bo, nullptr, out,
                                              nullptr, nullptr, Dc, Dc);
}

// Round 5
// 132.796 us; speedup vs baseline: 3.1448x; 1.0228x over previous
//
#include <hip/hip_runtime.h>
#include <cstdint>

// ---------------------------------------------------------------------------
// GQA cross-attention, bf16-MFMA pipeline (4 dispatches):
//   prep_k   : X,E -> bf16 casts ; Wq,Wo,Wk|Wv -> transposed bf16
//   qkv_k    : Q-proj (+RoPE, *0.125*log2e -> Qb) and KV-proj (K+RoPE -> Kb,
//              V -> transposed Vt) in ONE 768-block launch, 2-phase dbuf GEMM
//   attn_k   : flash attention, 4 waves x 32 q-rows, log2-domain softmax
//   oproj_k  : O-projection, f32 out
// ---------------------------------------------------------------------------

typedef __bf16 bf16x8 __attribute__((ext_vector_type(8)));
typedef __bf16 bf16x4v __attribute__((ext_vector_type(4)));
typedef float f32x4 __attribute__((ext_vector_type(4)));

#define MFMA16(a, b, c) __builtin_amdgcn_mfma_f32_16x16x32_bf16((a), (b), (c), 0, 0, 0)

constexpr int Bc = 2, TQc = 2048, TKc = 2048, Dc = 1024, Hc = 16, Gc = 4, HDc = 64;
constexpr float QSCALE = 0.18033688011112042f;  // 0.125 * log2(e): log2-domain scores

__device__ __forceinline__ ushort bfbits(float x) {  // native RNE f32->bf16
  __bf16 h = (__bf16)x;
  return __builtin_bit_cast(ushort, h);
}

__device__ __forceinline__ void async_lds16(void* lds, const void* g) {
  // wave-uniform LDS base; lane i lands at base + 16*i (guide §5)
  __builtin_amdgcn_global_load_lds((const __attribute__((address_space(1))) uint32_t*)g,
                                   (__attribute__((address_space(3))) uint32_t*)lds,
                                   16, 0, 0);
}

// ---------------- prep: casts (8192 blocks) + weight transposes (768) ------
__global__ __launch_bounds__(256) void prep_k(const float* __restrict__ X,
                                              const float* __restrict__ E,
                                              const float* __restrict__ Wq,
                                              const float* __restrict__ Wo,
                                              const float* __restrict__ Wk,
                                              const float* __restrict__ Wv,
                                              ushort* __restrict__ Xb,
                                              ushort* __restrict__ Eb,
                                              ushort* __restrict__ Wqt,
                                              ushort* __restrict__ Wot,
                                              ushort* __restrict__ Wkvt) {
  __shared__ float t[64][65];
  const int bid = blockIdx.x;
  if (bid < 8192) {  // cast: 4096 blocks X, 4096 blocks E
    const float* s = (bid < 4096) ? X : E;
    ushort* d = (bid < 4096) ? Xb : Eb;
    int i = (bid & 4095) * 256 + threadIdx.x;
    float4 v = reinterpret_cast<const float4*>(s)[i];
    ushort4 o;
    o.x = bfbits(v.x); o.y = bfbits(v.y); o.z = bfbits(v.z); o.w = bfbits(v.w);
    reinterpret_cast<ushort4*>(d)[i] = o;
    return;
  }
  // weight transpose: W[R][C] f32 -> Wt[C][R] bf16 (R = 1024 always)
  const int w = bid - 8192;           // [0, 768)
  const int z = w >> 8, rem = w & 255;
  const int bx = rem & 15, by = rem >> 4;
  const float* src;
  ushort* dst;
  int C, c0;
  if (z == 0)      { src = Wq; dst = Wqt; C = 1024; c0 = bx * 64; }
  else if (z == 1) { src = Wo; dst = Wot; C = 1024; c0 = bx * 64; }
  else {
    if (bx >= 8) return;
    if (bx < 4) { src = Wk; dst = Wkvt; }
    else        { src = Wv; dst = Wkvt + 256 * 1024; }
    C = 256; c0 = (bx & 3) * 64;
  }
  const int r0 = by * 64;
  const int tx = threadIdx.x & 63, ty = threadIdx.x >> 6;
#pragma unroll
  for (int i = 0; i < 16; ++i) {
    int r = i * 4 + ty;
    t[r][tx] = src[(size_t)(r0 + r) * C + c0 + tx];
  }
  __syncthreads();
#pragma unroll
  for (int i = 0; i < 16; ++i) {
    int c = i * 4 + ty;
    dst[(size_t)(c0 + c) * 1024 + r0 + tx] = bfbits(t[tx][c]);
  }
}

// ------- GEMM mainloop: 128x64 tile, BK=64, 2-phase double-buffered --------
// LDS XOR-swizzle (16B chunk ^= row&7): linear dest, pre-swizzled global
// source, swizzled ds_read (rule #21).  One barrier per K-step.
__device__ __forceinline__ void gemm_mainloop(const ushort* __restrict__ A,
                                              const ushort* __restrict__ Bt,
                                              int m0, int n0, int K,
                                              char* sA, char* sB,
                                              f32x4 acc[4][2]) {
  const int lane = threadIdx.x & 63, wid = threadIdx.x >> 6;
  const int l15 = lane & 15, l4 = lane >> 4;
  const int wr = (wid >> 1) * 64, wc = (wid & 1) * 32;
  const int srow = lane >> 3;                    // row within 8-row chunk
  const int scc = (lane & 7) ^ (srow & 7);       // pre-swizzled global chunk
  const int rxr = l15 & 7;                       // read-side row xor

  const int nsteps = K >> 6;
  // prologue: stage K-step 0 into buf 0
#pragma unroll
  for (int j = 0; j < 4; ++j) {
    int c = wid * 4 + j;
    async_lds16(sA + c * 1024, A + (size_t)(m0 + c * 8 + srow) * K + scc * 8);
  }
#pragma unroll
  for (int j = 0; j < 2; ++j) {
    int c = wid * 2 + j;
    async_lds16(sB + c * 1024, Bt + (size_t)(n0 + c * 8 + srow) * K + scc * 8);
  }
  __syncthreads();

  int buf = 0;
  for (int s2 = 0; s2 < nsteps; ++s2) {
    if (s2 + 1 < nsteps) {  // stage next step into the other buffer
      const int k0 = (s2 + 1) * 64;
      char* dA = sA + (buf ^ 1) * 16384;
      char* dB = sB + (buf ^ 1) * 8192;
#pragma unroll
      for (int j = 0; j < 4; ++j) {
        int c = wid * 4 + j;
        async_lds16(dA + c * 1024, A + (size_t)(m0 + c * 8 + srow) * K + k0 + scc * 8);
      }
#pragma unroll
      for (int j = 0; j < 2; ++j) {
        int c = wid * 2 + j;
        async_lds16(dB + c * 1024, Bt + (size_t)(n0 + c * 8 + srow) * K + k0 + scc * 8);
      }
    }
    const char* aB = sA + buf * 16384;
    const char* bB = sB + buf * 8192;
    bf16x8 af[2][4], bfr[2][2];
#pragma unroll
    for (int mi = 0; mi < 4; ++mi) {
      const int row = wr + mi * 16 + l15;
#pragma unroll
      for (int kk = 0; kk < 2; ++kk)
        af[kk][mi] = *reinterpret_cast<const bf16x8*>(
            aB + row * 128 + (((l4 + kk * 4) ^ rxr) << 4));
    }
#pragma unroll
    for (int ni = 0; ni < 2; ++ni) {
      const int row = wc + ni * 16 + l15;
#pragma unroll
      for (int kk = 0; kk < 2; ++kk)
        bfr[kk][ni] = *reinterpret_cast<const bf16x8*>(
            bB + row * 128 + (((l4 + kk * 4) ^ rxr) << 4));
    }
#pragma unroll
    for (int kk = 0; kk < 2; ++kk)
#pragma unroll
      for (int mi = 0; mi < 4; ++mi)
#pragma unroll
        for (int ni = 0; ni < 2; ++ni)
          acc[mi][ni] = MFMA16(af[kk][mi], bfr[kk][ni], acc[mi][ni]);
    __syncthreads();  // drains vmcnt(0): next tile landed; buf reads done
    buf ^= 1;
  }
}

// ------- shared GEMM epilogue.  mode 0: f32 C+bias. mode 1: Q+RoPE+scale.
// mode 2: N=512, col<256 K+RoPE; col>=256 V -> transposed Vt. --------------
__device__ __forceinline__ void gemm_epilogue(f32x4 acc[4][2], int mode, int m0,
                                              int n0, const float* b0,
                                              const float* b1, float* Cf,
                                              ushort* U0, ushort* U1, int N) {
  const int lane = threadIdx.x & 63, wid = threadIdx.x >> 6;
  const int l15 = lane & 15, l4 = lane >> 4;
  const int wr = (wid >> 1) * 64, wc = (wid & 1) * 32;
#pragma unroll
  for (int ni = 0; ni < 2; ++ni) {
    const int col = n0 + wc + ni * 16 + l15;
    if (mode == 0) {
      const float bv = b0[col];
#pragma unroll
      for (int mi = 0; mi < 4; ++mi) {
        const int rowb = m0 + wr + mi * 16 + l4 * 4;
#pragma unroll
        for (int r = 0; r < 4; ++r)
          Cf[(size_t)(rowb + r) * N + col] = acc[mi][ni][r] + bv;
      }
    } else if (mode == 1) {
      const int h = col >> 6, d = col & 63, fi = d >> 1, odd = d & 1;
      const float div = __expf(-0.28782313662425572f * (float)fi);  // -ln(1e4)/32
      const float bv = b0[col];
#pragma unroll
      for (int mi = 0; mi < 4; ++mi) {
        const int rowb = m0 + wr + mi * 16 + l4 * 4;
#pragma unroll
        for (int r = 0; r < 4; ++r) {
          const int row = rowb + r, b = row >> 11, t = row & 2047;
          const float val = acc[mi][ni][r] + bv;
          const float prt = __shfl_xor(val, 1);  // partner column (d^1)
          float sn, cs;
          __sincosf((float)t * div, &sn, &cs);
          const float o = odd ? (prt * sn + val * cs) : (val * cs - prt * sn);
          U0[(((size_t)(b * Hc + h)) * TQc + t) * HDc + d] = bfbits(o * QSCALE);
        }
      }
    } else {
      if (col < 256) {  // K path: RoPE -> Kb[b][g][t][d]
        const int g = col >> 6, d = col & 63, fi = d >> 1, odd = d & 1;
        const float div = __expf(-0.28782313662425572f * (float)fi);
        const float bv = b0[col];
#pragma unroll
        for (int mi = 0; mi < 4; ++mi) {
          const int rowb = m0 + wr + mi * 16 + l4 * 4;
#pragma unroll
          for (int r = 0; r < 4; ++r) {
            const int row = rowb + r, b = row >> 11, t = row & 2047;
            const float val = acc[mi][ni][r] + bv;
            const float prt = __shfl_xor(val, 1);
            float sn, cs;
            __sincosf((float)t * div, &sn, &cs);
            const float o = odd ? (prt * sn + val * cs) : (val * cs - prt * sn);
            U0[(((size_t)(b * Gc + g)) * TKc + t) * HDc + d] = bfbits(o);
          }
        }
      } else {  // V path: transpose-write Vt[b][g][d][t]
        const int c2 = col - 256;
        const int g = c2 >> 6, d = c2 & 63;
        const float bv = b1[c2];
#pragma unroll
        for (int mi = 0; mi < 4; ++mi) {
          const int rowb = m0 + wr + mi * 16 + l4 * 4;
          const int b = rowb >> 11, t0 = rowb & 2047;
          ushort4 w;
          w.x = bfbits(acc[mi][ni][0] + bv);
          w.y = bfbits(acc[mi][ni][1] + bv);
          w.z = bfbits(acc[mi][ni][2] + bv);
          w.w = bfbits(acc[mi][ni][3] + bv);
          *reinterpret_cast<ushort4*>(
              &U1[(((size_t)(b * Gc + g)) * HDc + d) * TKc + t0]) = w;
        }
      }
    }
  }
}

// ------- Q-proj (blocks 0..511) + KV-proj (512..767), one launch -----------
__global__ __launch_bounds__(256) void qkv_k(const ushort* __restrict__ Xb,
                                             const ushort* __restrict__ Eb,
                                             const ushort* __restrict__ Wqt,
                                             const ushort* __restrict__ Wkvt,
                                             const float* __restrict__ bq,
                                             const float* __restrict__ bk,
                                             const float* __restrict__ bv,
                                             ushort* __restrict__ Qb,
                                             ushort* __restrict__ Kb,
                                             ushort* __restrict__ Vt) {
  __shared__ __attribute__((aligned(16))) char smem[48 * 1024];
  const int bid = blockIdx.x;
  const ushort *A, *Bt;
  const float *b0, *b1 = nullptr;
  ushort *U0, *U1 = nullptr;
  int mode, tb, tn;
  if (bid < 512) { A = Xb; Bt = Wqt; b0 = bq; U0 = Qb; mode = 1; tb = bid; tn = 16; }
  else { A = Eb; Bt = Wkvt; b0 = bk; b1 = bv; U0 = Kb; U1 = Vt; mode = 2; tb = bid - 512; tn = 8; }
  const int m0 = (tb / tn) * 128, n0 = (tb % tn) * 64;
  const f32x4 z = {0.f, 0.f, 0.f, 0.f};
  f32x4 acc[4][2] = {{z, z}, {z, z}, {z, z}, {z, z}};
  gemm_mainloop(A, Bt, m0, n0, 1024, smem, smem + 32768, acc);
  gemm_epilogue(acc, mode, m0, n0, b0, b1, nullptr, U0, U1, 0);
}

// ------- O-projection: out = Ob * Wot^T + bo (f32) -------------------------
__global__ __launch_bounds__(256) void oproj_k(const ushort* __restrict__ Ob,
                                               const ushort* __restrict__ Wot,
                                               const float* __restrict__ bo,
                                               float* __restrict__ out) {
  __shared__ __attribute__((aligned(16))) char smem[48 * 1024];
  const int bid = blockIdx.x;
  const int m0 = (bid >> 4) * 128, n0 = (bid & 15) * 64;
  const f32x4 z = {0.f, 0.f, 0.f, 0.f};
  f32x4 acc[4][2] = {{z, z}, {z, z}, {z, z}, {z, z}};
  gemm_mainloop(Ob, Wot, m0, n0, 1024, smem, smem + 32768, acc);
  gemm_epilogue(acc, 0, m0, n0, bo, nullptr, out, nullptr, nullptr, 1024);
}

// ------- flash attention, LDS-staged K/V, swapped-QK^T, log2 softmax -------
// Qb[b][h][t][64] (pre-scaled by 0.125*log2e), Kb[b][g][t][64], Vt[b][g][64][t].
// 256 thr = 4 waves x 32 q-rows (two 16-row halves), KVBLK=64, dbuf LDS.
__global__ __launch_bounds__(256) void attn_k(const ushort* __restrict__ Qg,
                                              const ushort* __restrict__ Kg,
                                              const ushort* __restrict__ Vg,
                                              ushort* __restrict__ Ob) {
  __shared__ __attribute__((aligned(16))) char smem[48 * 1024];
  const int lane = threadIdx.x & 63, wid = threadIdx.x >> 6;
  const int l15 = lane & 15, l4 = lane >> 4;
  // XCD-aware decode: bid&7 = (b,g) group -> each XCD L2 caches ONE group's K/V
  const int bid = blockIdx.x;  // 512 blocks
  const int bg = bid & 7, pos = bid >> 3;
  const int b = bg >> 2, g = bg & 3;
  const int h = g * 4 + (pos >> 4);
  const int q0 = (pos & 15) * 128 + wid * 32;
  const ushort* Qp = Qg + ((size_t)(b * Hc + h)) * TQc * HDc;
  const ushort* Kp = Kg + ((size_t)(b * Gc + g)) * TKc * HDc;
  const ushort* Vp = Vg + ((size_t)(b * Gc + g)) * HDc * TKc;
  char* sK = smem;                       // [2][8192]
  char* sV = smem + 16384;               // [2][8192]
  char* pbA = smem + 32768 + wid * 4096; // P half A [16][64] bf16
  char* pbB = pbA + 2048;                // P half B
  const int rx = (l15 & 7) << 4;         // P-row swizzle
  const int swz = l15 & 7;               // K/V fragment chunk swizzle

  // staging: wave covers tile rows wid*16..wid*16+15 (2x 1KB for K, 2x for V)
  const int sr = wid * 16 + (lane >> 3);
  const int sc = (lane & 7) ^ ((lane >> 3) & 7);
  const char* Kst = (const char*)Kp + (size_t)sr * 128 + sc * 16;
  const char* Vst = (const char*)Vp + (size_t)sr * (TKc * 2) + sc * 16;

  // Q fragments (B operand), two 16-row halves
  bf16x8 qA0 = *reinterpret_cast<const bf16x8*>(Qp + (size_t)(q0 + l15) * HDc + l4 * 8);
  bf16x8 qA1 = *reinterpret_cast<const bf16x8*>(Qp + (size_t)(q0 + l15) * HDc + 32 + l4 * 8);
  bf16x8 qB0 = *reinterpret_cast<const bf16x8*>(Qp + (size_t)(q0 + 16 + l15) * HDc + l4 * 8);
  bf16x8 qB1 = *reinterpret_cast<const bf16x8*>(Qp + (size_t)(q0 + 16 + l15) * HDc + 32 + l4 * 8);

  float mA = -INFINITY, lA = 0.f, mB = -INFINITY, lB = 0.f;
  const f32x4 z = {0.f, 0.f, 0.f, 0.f};
  f32x4 accA[4] = {z, z, z, z}, accB[4] = {z, z, z, z};

  constexpr int NT = TKc / 64;
  // prologue: stage tile 0 into buffer 0
  async_lds16(sK + wid * 2048, Kst);
  async_lds16(sK + wid * 2048 + 1024, Kst + 1024);
  async_lds16(sV + wid * 2048, Vst);
  async_lds16(sV + wid * 2048 + 1024, Vst + 32768);
  __syncthreads();
  const char* KstN = Kst + 8192;
  const char* VstN = Vst + 128;

  // softmax for one 16-row half (lane-local rows, log2 domain)
  auto softmax_half = [&](f32x4 s[4], float& m, float& l, f32x4* acc, char* pbh) {
    float pm = fmaxf(fmaxf(fmaxf(s[0][0], s[0][1]), fmaxf(s[0][2], s[0][3])),
                     fmaxf(fmaxf(s[1][0], s[1][1]), fmaxf(s[1][2], s[1][3])));
    pm = fmaxf(pm, fmaxf(fmaxf(fmaxf(s[2][0], s[2][1]), fmaxf(s[2][2], s[2][3])),
                         fmaxf(fmaxf(s[3][0], s[3][1]), fmaxf(s[3][2], s[3][3]))));
    pm = fmaxf(pm, __shfl_xor(pm, 16));
    pm = fmaxf(pm, __shfl_xor(pm, 32));
    if (!__all(pm - m <= 11.5f)) {  // T13 defer-max (log2 units)
      float mn = fmaxf(m, pm);
      float sc2 = exp2f(m - mn);
      m = mn;
      l *= sc2;
#pragma unroll
      for (int df = 0; df < 4; ++df) acc[df] *= sc2;
    }
    float ps = 0.f;
#pragma unroll
    for (int nf = 0; nf < 4; ++nf)
#pragma unroll
      for (int r = 0; r < 4; ++r) {
        float p = exp2f(s[nf][r] - m);
        s[nf][r] = p;
        ps += p;
      }
    ps += __shfl_xor(ps, 16);
    ps += __shfl_xor(ps, 32);
    l += ps;
#pragma unroll
    for (int nf = 0; nf < 4; ++nf) {
      bf16x4v pv;
      pv[0] = (__bf16)s[nf][0];
      pv[1] = (__bf16)s[nf][1];
      pv[2] = (__bf16)s[nf][2];
      pv[3] = (__bf16)s[nf][3];
      *reinterpret_cast<uint2*>(pbh + l15 * 128 + ((nf * 32 + l4 * 8) ^ rx)) =
          __builtin_bit_cast(uint2, pv);
    }
  };

  int buf = 0;
  for (int kt = 0; kt < NT; ++kt) {
    if (kt + 1 < NT) {  // issue next-tile loads; they complete under compute
      char* dK = sK + (buf ^ 1) * 8192 + wid * 2048;
      char* dV = sV + (buf ^ 1) * 8192 + wid * 2048;
      async_lds16(dK, KstN);
      async_lds16(dK + 1024, KstN + 1024);
      async_lds16(dV, VstN);
      async_lds16(dV + 1024, VstN + 32768);
      KstN += 8192;
      VstN += 128;
    }
    const char* sKb = sK + buf * 8192;
    const char* sVb = sV + buf * 8192;

    // QK^T both halves share the K fragments: S^T[key][q]
    f32x4 sa[4] = {z, z, z, z}, sb[4] = {z, z, z, z};
#pragma unroll
    for (int nf = 0; nf < 4; ++nf) {
      const char* krow = sKb + (nf * 16 + l15) * 128;
      bf16x8 k0 = *reinterpret_cast<const bf16x8*>(krow + ((l4 ^ swz) << 4));
      bf16x8 k1 = *reinterpret_cast<const bf16x8*>(krow + (((4 + l4) ^ swz) << 4));
      sa[nf] = MFMA16(k0, qA0, sa[nf]);
      sa[nf] = MFMA16(k1, qA1, sa[nf]);
      sb[nf] = MFMA16(k0, qB0, sb[nf]);
      sb[nf] = MFMA16(k1, qB1, sb[nf]);
    }
    // V fragments (shared by both halves): B[k=key][n=d]
    bf16x8 va[4][2];
#pragma unroll
    for (int df = 0; df < 4; ++df) {
      const char* vrow = sVb + (df * 16 + l15) * 128;
      va[df][0] = *reinterpret_cast<const bf16x8*>(vrow + ((l4 ^ swz) << 4));
      va[df][1] = *reinterpret_cast<const bf16x8*>(vrow + (((4 + l4) ^ swz) << 4));
    }

    softmax_half(sa, mA, lA, accA, pbA);
    softmax_half(sb, mB, lB, accB, pbB);

    // PV: A = P[q][key] from LDS, B = V^T fragments
    bf16x8 apA0 = *reinterpret_cast<const bf16x8*>(pbA + l15 * 128 + ((l4 * 16) ^ rx));
    bf16x8 apA1 = *reinterpret_cast<const bf16x8*>(pbA + l15 * 128 + ((64 + l4 * 16) ^ rx));
    bf16x8 apB0 = *reinterpret_cast<const bf16x8*>(pbB + l15 * 128 + ((l4 * 16) ^ rx));
    bf16x8 apB1 = *reinterpret_cast<const bf16x8*>(pbB + l15 * 128 + ((64 + l4 * 16) ^ rx));
#pragma unroll
    for (int df = 0; df < 4; ++df) {
      accA[df] = MFMA16(apA1, va[df][1], MFMA16(apA0, va[df][0], accA[df]));
      accB[df] = MFMA16(apB1, va[df][1], MFMA16(apB0, va[df][0], accB[df]));
    }

    __syncthreads();  // drains vmcnt(0): next tile landed; all waves done reading
    buf ^= 1;
  }

  // epilogue: half A rows q0+l4*4+r, half B rows q0+16+l4*4+r
  float invA[4], invB[4];
#pragma unroll
  for (int r = 0; r < 4; ++r) {
    invA[r] = 1.f / __shfl(lA, l4 * 4 + r);
    invB[r] = 1.f / __shfl(lB, l4 * 4 + r);
  }
#pragma unroll
  for (int df = 0; df < 4; ++df) {
    const int col = h * HDc + df * 16 + l15;
#pragma unroll
    for (int r = 0; r < 4; ++r) {
      const int rowA = q0 + l4 * 4 + r;
      Ob[((size_t)b * TQc + rowA) * Dc + col] = bfbits(accA[df][r] * invA[r]);
      Ob[((size_t)b * TQc + rowA + 16) * Dc + col] = bfbits(accB[df][r] * invB[r]);
    }
  }
}

// ---------------------------------------------------------------------------
extern "C" void kernel_launch(void* const* d_in, const int* in_sizes, int n_in,
                              void* d_out, int out_size, void* d_ws, size_t ws_size,
                              hipStream_t stream) {
  const float* X  = (const float*)d_in[0];
  const float* E  = (const float*)d_in[1];
  const float* Wq = (const float*)d_in[2];
  const float* bq = (const float*)d_in[3];
  const float* Wk = (const float*)d_in[4];
  const float* bk = (const float*)d_in[5];
  const float* Wv = (const float*)d_in[6];
  const float* bv = (const float*)d_in[7];
  const float* Wo = (const float*)d_in[8];
  const float* bo = (const float*)d_in[9];
  float* out = (float*)d_out;
  char* ws = (char*)d_ws;

  const size_t MB = 1ull << 20;
  if (ws_size < 42 * MB) return;  // tripwire: reproduces stub failure signature

  ushort* Xb   = (ushort*)(ws + 0 * MB);   // [4096][1024] bf16
  ushort* Eb   = (ushort*)(ws + 8 * MB);   // [4096][1024]
  ushort* Wqt  = (ushort*)(ws + 16 * MB);  // [1024][1024]
  ushort* Wkvt = (ushort*)(ws + 18 * MB);  // [512][1024] (Wk^T | Wv^T)
  ushort* Wot  = (ushort*)(ws + 19 * MB);  // [1024][1024]
  ushort* Qb   = (ushort*)(ws + 21 * MB);  // [2][16][2048][64]
  ushort* Kb   = (ushort*)(ws + 29 * MB);  // [2][4][2048][64]
  ushort* Vt   = (ushort*)(ws + 31 * MB);  // [2][4][64][2048]
  ushort* Ob   = (ushort*)(ws + 33 * MB);  // [2][2048][1024]

  // 1. casts + weight transposes
  prep_k<<<dim3(8960), 256, 0, stream>>>(X, E, Wq, Wo, Wk, Wv, Xb, Eb, Wqt, Wot, Wkvt);
  // 2. Q-proj (+RoPE+scale) and KV-proj (K+RoPE, V^T) concurrently
  qkv_k<<<dim3(768), 256, 0, stream>>>(Xb, Eb, Wqt, Wkvt, bq, bk, bv, Qb, Kb, Vt);
  // 3. attention -> Ob
  attn_k<<<dim3(512), 256, 0, stream>>>(Qb, Kb, Vt, Ob);
  // 4. output projection -> out (f32)
  oproj_k<<<dim3(512), 256, 0, stream>>>(Ob, Wot, bo, out);
}

// Round 6
// 120.350 us; speedup vs baseline: 3.4700x; 1.1034x over previous
//
#include <hip/hip_runtime.h>
#include <cstdint>

// ---------------------------------------------------------------------------
// GQA cross-attention, bf16-MFMA pipeline (4 dispatches):
//   prep_k   : X,E -> bf16 casts ; Wq,Wo,Wk|Wv -> transposed bf16
//   qkv_k    : Q-proj (+RoPE, *0.125*log2e -> Qb) and KV-proj (K+RoPE -> Kb,
//              V -> transposed Vt) in ONE 768-block launch, 2-phase dbuf GEMM
//   attn_k   : flash attention, 8 waves x 16 q-rows (512 thr), log2 softmax
//   oproj_k  : O-projection, f32 out
// ---------------------------------------------------------------------------

typedef __bf16 bf16x8 __attribute__((ext_vector_type(8)));
typedef __bf16 bf16x4v __attribute__((ext_vector_type(4)));
typedef float f32x4 __attribute__((ext_vector_type(4)));

#define MFMA16(a, b, c) __builtin_amdgcn_mfma_f32_16x16x32_bf16((a), (b), (c), 0, 0, 0)

constexpr int Bc = 2, TQc = 2048, TKc = 2048, Dc = 1024, Hc = 16, Gc = 4, HDc = 64;
constexpr float QSCALE = 0.18033688011112042f;  // 0.125 * log2(e): log2-domain scores

__device__ __forceinline__ ushort bfbits(float x) {  // native RNE f32->bf16
  __bf16 h = (__bf16)x;
  return __builtin_bit_cast(ushort, h);
}

__device__ __forceinline__ void async_lds16(void* lds, const void* g) {
  // wave-uniform LDS base; lane i lands at base + 16*i (guide §5)
  __builtin_amdgcn_global_load_lds((const __attribute__((address_space(1))) uint32_t*)g,
                                   (__attribute__((address_space(3))) uint32_t*)lds,
                                   16, 0, 0);
}

// ---------------- prep: casts (8192 blocks) + weight transposes (768) ------
__global__ __launch_bounds__(256) void prep_k(const float* __restrict__ X,
                                              const float* __restrict__ E,
                                              const float* __restrict__ Wq,
                                              const float* __restrict__ Wo,
                                              const float* __restrict__ Wk,
                                              const float* __restrict__ Wv,
                                              ushort* __restrict__ Xb,
                                              ushort* __restrict__ Eb,
                                              ushort* __restrict__ Wqt,
                                              ushort* __restrict__ Wot,
                                              ushort* __restrict__ Wkvt) {
  __shared__ float t[64][65];
  const int bid = blockIdx.x;
  if (bid < 8192) {  // cast: 4096 blocks X, 4096 blocks E
    const float* s = (bid < 4096) ? X : E;
    ushort* d = (bid < 4096) ? Xb : Eb;
    int i = (bid & 4095) * 256 + threadIdx.x;
    float4 v = reinterpret_cast<const float4*>(s)[i];
    ushort4 o;
    o.x = bfbits(v.x); o.y = bfbits(v.y); o.z = bfbits(v.z); o.w = bfbits(v.w);
    reinterpret_cast<ushort4*>(d)[i] = o;
    return;
  }
  // weight transpose: W[R][C] f32 -> Wt[C][R] bf16 (R = 1024 always)
  const int w = bid - 8192;           // [0, 768)
  const int z = w >> 8, rem = w & 255;
  const int bx = rem & 15, by = rem >> 4;
  const float* src;
  ushort* dst;
  int C, c0;
  if (z == 0)      { src = Wq; dst = Wqt; C = 1024; c0 = bx * 64; }
  else if (z == 1) { src = Wo; dst = Wot; C = 1024; c0 = bx * 64; }
  else {
    if (bx >= 8) return;
    if (bx < 4) { src = Wk; dst = Wkvt; }
    else        { src = Wv; dst = Wkvt + 256 * 1024; }
    C = 256; c0 = (bx & 3) * 64;
  }
  const int r0 = by * 64;
  const int tx = threadIdx.x & 63, ty = threadIdx.x >> 6;
#pragma unroll
  for (int i = 0; i < 16; ++i) {
    int r = i * 4 + ty;
    t[r][tx] = src[(size_t)(r0 + r) * C + c0 + tx];
  }
  __syncthreads();
#pragma unroll
  for (int i = 0; i < 16; ++i) {
    int c = i * 4 + ty;
    dst[(size_t)(c0 + c) * 1024 + r0 + tx] = bfbits(t[tx][c]);
  }
}

// ------- GEMM mainloop: 128x64 tile, BK=64, 2-phase double-buffered --------
// LDS XOR-swizzle (16B chunk ^= row&7): linear dest, pre-swizzled global
// source, swizzled ds_read (rule #21).  One barrier per K-step.
__device__ __forceinline__ void gemm_mainloop(const ushort* __restrict__ A,
                                              const ushort* __restrict__ Bt,
                                              int m0, int n0, int K,
                                              char* sA, char* sB,
                                              f32x4 acc[4][2]) {
  const int lane = threadIdx.x & 63, wid = threadIdx.x >> 6;
  const int l15 = lane & 15, l4 = lane >> 4;
  const int wr = (wid >> 1) * 64, wc = (wid & 1) * 32;
  const int srow = lane >> 3;                    // row within 8-row chunk
  const int scc = (lane & 7) ^ (srow & 7);       // pre-swizzled global chunk
  const int rxr = l15 & 7;                       // read-side row xor

  const int nsteps = K >> 6;
  // prologue: stage K-step 0 into buf 0
#pragma unroll
  for (int j = 0; j < 4; ++j) {
    int c = wid * 4 + j;
    async_lds16(sA + c * 1024, A + (size_t)(m0 + c * 8 + srow) * K + scc * 8);
  }
#pragma unroll
  for (int j = 0; j < 2; ++j) {
    int c = wid * 2 + j;
    async_lds16(sB + c * 1024, Bt + (size_t)(n0 + c * 8 + srow) * K + scc * 8);
  }
  __syncthreads();

  int buf = 0;
  for (int s2 = 0; s2 < nsteps; ++s2) {
    if (s2 + 1 < nsteps) {  // stage next step into the other buffer
      const int k0 = (s2 + 1) * 64;
      char* dA = sA + (buf ^ 1) * 16384;
      char* dB = sB + (buf ^ 1) * 8192;
#pragma unroll
      for (int j = 0; j < 4; ++j) {
        int c = wid * 4 + j;
        async_lds16(dA + c * 1024, A + (size_t)(m0 + c * 8 + srow) * K + k0 + scc * 8);
      }
#pragma unroll
      for (int j = 0; j < 2; ++j) {
        int c = wid * 2 + j;
        async_lds16(dB + c * 1024, Bt + (size_t)(n0 + c * 8 + srow) * K + k0 + scc * 8);
      }
    }
    const char* aB = sA + buf * 16384;
    const char* bB = sB + buf * 8192;
    bf16x8 af[2][4], bfr[2][2];
#pragma unroll
    for (int mi = 0; mi < 4; ++mi) {
      const int row = wr + mi * 16 + l15;
#pragma unroll
      for (int kk = 0; kk < 2; ++kk)
        af[kk][mi] = *reinterpret_cast<const bf16x8*>(
            aB + row * 128 + (((l4 + kk * 4) ^ rxr) << 4));
    }
#pragma unroll
    for (int ni = 0; ni < 2; ++ni) {
      const int row = wc + ni * 16 + l15;
#pragma unroll
      for (int kk = 0; kk < 2; ++kk)
        bfr[kk][ni] = *reinterpret_cast<const bf16x8*>(
            bB + row * 128 + (((l4 + kk * 4) ^ rxr) << 4));
    }
#pragma unroll
    for (int kk = 0; kk < 2; ++kk)
#pragma unroll
      for (int mi = 0; mi < 4; ++mi)
#pragma unroll
        for (int ni = 0; ni < 2; ++ni)
          acc[mi][ni] = MFMA16(af[kk][mi], bfr[kk][ni], acc[mi][ni]);
    __syncthreads();  // drains vmcnt(0): next tile landed; buf reads done
    buf ^= 1;
  }
}

// ------- shared GEMM epilogue.  mode 0: f32 C+bias. mode 1: Q+RoPE+scale.
// mode 2: N=512, col<256 K+RoPE; col>=256 V -> transposed Vt. --------------
__device__ __forceinline__ void gemm_epilogue(f32x4 acc[4][2], int mode, int m0,
                                              int n0, const float* b0,
                                              const float* b1, float* Cf,
                                              ushort* U0, ushort* U1, int N) {
  const int lane = threadIdx.x & 63, wid = threadIdx.x >> 6;
  const int l15 = lane & 15, l4 = lane >> 4;
  const int wr = (wid >> 1) * 64, wc = (wid & 1) * 32;
#pragma unroll
  for (int ni = 0; ni < 2; ++ni) {
    const int col = n0 + wc + ni * 16 + l15;
    if (mode == 0) {
      const float bv = b0[col];
#pragma unroll
      for (int mi = 0; mi < 4; ++mi) {
        const int rowb = m0 + wr + mi * 16 + l4 * 4;
#pragma unroll
        for (int r = 0; r < 4; ++r)
          Cf[(size_t)(rowb + r) * N + col] = acc[mi][ni][r] + bv;
      }
    } else if (mode == 1) {
      const int h = col >> 6, d = col & 63, fi = d >> 1, odd = d & 1;
      const float div = __expf(-0.28782313662425572f * (float)fi);  // -ln(1e4)/32
      const float bv = b0[col];
#pragma unroll
      for (int mi = 0; mi < 4; ++mi) {
        const int rowb = m0 + wr + mi * 16 + l4 * 4;
#pragma unroll
        for (int r = 0; r < 4; ++r) {
          const int row = rowb + r, b = row >> 11, t = row & 2047;
          const float val = acc[mi][ni][r] + bv;
          const float prt = __shfl_xor(val, 1);  // partner column (d^1)
          float sn, cs;
          __sincosf((float)t * div, &sn, &cs);
          const float o = odd ? (prt * sn + val * cs) : (val * cs - prt * sn);
          U0[(((size_t)(b * Hc + h)) * TQc + t) * HDc + d] = bfbits(o * QSCALE);
        }
      }
    } else {
      if (col < 256) {  // K path: RoPE -> Kb[b][g][t][d]
        const int g = col >> 6, d = col & 63, fi = d >> 1, odd = d & 1;
        const float div = __expf(-0.28782313662425572f * (float)fi);
        const float bv = b0[col];
#pragma unroll
        for (int mi = 0; mi < 4; ++mi) {
          const int rowb = m0 + wr + mi * 16 + l4 * 4;
#pragma unroll
          for (int r = 0; r < 4; ++r) {
            const int row = rowb + r, b = row >> 11, t = row & 2047;
            const float val = acc[mi][ni][r] + bv;
            const float prt = __shfl_xor(val, 1);
            float sn, cs;
            __sincosf((float)t * div, &sn, &cs);
            const float o = odd ? (prt * sn + val * cs) : (val * cs - prt * sn);
            U0[(((size_t)(b * Gc + g)) * TKc + t) * HDc + d] = bfbits(o);
          }
        }
      } else {  // V path: transpose-write Vt[b][g][d][t]
        const int c2 = col - 256;
        const int g = c2 >> 6, d = c2 & 63;
        const float bv = b1[c2];
#pragma unroll
        for (int mi = 0; mi < 4; ++mi) {
          const int rowb = m0 + wr + mi * 16 + l4 * 4;
          const int b = rowb >> 11, t0 = rowb & 2047;
          ushort4 w;
          w.x = bfbits(acc[mi][ni][0] + bv);
          w.y = bfbits(acc[mi][ni][1] + bv);
          w.z = bfbits(acc[mi][ni][2] + bv);
          w.w = bfbits(acc[mi][ni][3] + bv);
          *reinterpret_cast<ushort4*>(
              &U1[(((size_t)(b * Gc + g)) * HDc + d) * TKc + t0]) = w;
        }
      }
    }
  }
}

// ------- Q-proj (blocks 0..511) + KV-proj (512..767), one launch -----------
__global__ __launch_bounds__(256) void qkv_k(const ushort* __restrict__ Xb,
                                             const ushort* __restrict__ Eb,
                                             const ushort* __restrict__ Wqt,
                                             const ushort* __restrict__ Wkvt,
                                             const float* __restrict__ bq,
                                             const float* __restrict__ bk,
                                             const float* __restrict__ bv,
                                             ushort* __restrict__ Qb,
                                             ushort* __restrict__ Kb,
                                             ushort* __restrict__ Vt) {
  __shared__ __attribute__((aligned(16))) char smem[48 * 1024];
  const int bid = blockIdx.x;
  const ushort *A, *Bt;
  const float *b0, *b1 = nullptr;
  ushort *U0, *U1 = nullptr;
  int mode, tb, tn;
  if (bid < 512) { A = Xb; Bt = Wqt; b0 = bq; U0 = Qb; mode = 1; tb = bid; tn = 16; }
  else { A = Eb; Bt = Wkvt; b0 = bk; b1 = bv; U0 = Kb; U1 = Vt; mode = 2; tb = bid - 512; tn = 8; }
  const int m0 = (tb / tn) * 128, n0 = (tb % tn) * 64;
  const f32x4 z = {0.f, 0.f, 0.f, 0.f};
  f32x4 acc[4][2] = {{z, z}, {z, z}, {z, z}, {z, z}};
  gemm_mainloop(A, Bt, m0, n0, 1024, smem, smem + 32768, acc);
  gemm_epilogue(acc, mode, m0, n0, b0, b1, nullptr, U0, U1, 0);
}

// ------- O-projection: out = Ob * Wot^T + bo (f32) -------------------------
__global__ __launch_bounds__(256) void oproj_k(const ushort* __restrict__ Ob,
                                               const ushort* __restrict__ Wot,
                                               const float* __restrict__ bo,
                                               float* __restrict__ out) {
  __shared__ __attribute__((aligned(16))) char smem[48 * 1024];
  const int bid = blockIdx.x;
  const int m0 = (bid >> 4) * 128, n0 = (bid & 15) * 64;
  const f32x4 z = {0.f, 0.f, 0.f, 0.f};
  f32x4 acc[4][2] = {{z, z}, {z, z}, {z, z}, {z, z}};
  gemm_mainloop(Ob, Wot, m0, n0, 1024, smem, smem + 32768, acc);
  gemm_epilogue(acc, 0, m0, n0, bo, nullptr, out, nullptr, nullptr, 1024);
}

// ------- flash attention, LDS-staged K/V, swapped-QK^T, log2 softmax -------
// Qb[b][h][t][64] (pre-scaled by 0.125*log2e), Kb[b][g][t][64], Vt[b][g][64][t].
// 512 thr = 8 waves x 16 q-rows (QBLK=128), KVBLK=64, double-buffered LDS.
// K/V tiles: 64 rows x 128B, XOR-swizzled (chunk ^= row&7): linear LDS dest,
// pre-swizzled per-lane GLOBAL source, swizzled ds_read (rule #21).
__global__ __launch_bounds__(512, 4) void attn_k(const ushort* __restrict__ Qg,
                                                 const ushort* __restrict__ Kg,
                                                 const ushort* __restrict__ Vg,
                                                 ushort* __restrict__ Ob) {
  __shared__ __attribute__((aligned(16))) char smem[48 * 1024];
  const int lane = threadIdx.x & 63, wid = threadIdx.x >> 6;
  const int l15 = lane & 15, l4 = lane >> 4;
  // XCD-aware decode: bid&7 = (b,g) group -> each XCD L2 caches ONE group's K/V
  const int bid = blockIdx.x;  // 512 blocks
  const int bg = bid & 7, pos = bid >> 3;
  const int b = bg >> 2, g = bg & 3;
  const int h = g * 4 + (pos >> 4);
  const int q0 = (pos & 15) * 128 + wid * 16;
  const ushort* Qp = Qg + ((size_t)(b * Hc + h)) * TQc * HDc;
  const ushort* Kp = Kg + ((size_t)(b * Gc + g)) * TKc * HDc;
  const ushort* Vp = Vg + ((size_t)(b * Gc + g)) * HDc * TKc;
  char* sK = smem;                         // [2][8192]
  char* sV = smem + 16384;                 // [2][8192]
  char* pb = smem + 32768 + wid * 2048;    // per-wave P tile [16][64] bf16
  const int rx = (l15 & 7) << 4;           // P-row swizzle
  const int swz = l15 & 7;                 // K/V fragment chunk swizzle

  // staging geometry: wave stages 1KB of K and 1KB of V per tile
  const int sr = wid * 8 + (lane >> 3);              // tile row this lane fills
  const int sc = (lane & 7) ^ ((lane >> 3) & 7);     // pre-swizzled src chunk
  const char* Kb8 = (const char*)Kp;
  const char* Vb8 = (const char*)Vp;

  // Q (B operand): col n=l15 -> q=q0+l15, k=l4*8+j -> d
  bf16x8 bq0 = *reinterpret_cast<const bf16x8*>(Qp + (size_t)(q0 + l15) * HDc + l4 * 8);
  bf16x8 bq1 = *reinterpret_cast<const bf16x8*>(Qp + (size_t)(q0 + l15) * HDc + 32 + l4 * 8);

  float m = -INFINITY, l = 0.f;
  const f32x4 z = {0.f, 0.f, 0.f, 0.f};
  f32x4 accO[4] = {z, z, z, z};

  constexpr int NT = TKc / 64;
  // prologue: stage tile 0 into buffer 0
  async_lds16(sK + wid * 1024, Kb8 + (size_t)sr * 128 + sc * 16);
  async_lds16(sV + wid * 1024, Vb8 + (size_t)sr * (TKc * 2) + sc * 16);
  __syncthreads();

  int buf = 0;
  for (int kt = 0; kt < NT; ++kt) {
    if (kt + 1 < NT) {  // issue next-tile loads; they complete under compute
      char* dK = sK + (buf ^ 1) * 8192 + wid * 1024;
      char* dV = sV + (buf ^ 1) * 8192 + wid * 1024;
      async_lds16(dK, Kb8 + ((size_t)(kt + 1) * 64 + sr) * 128 + sc * 16);
      async_lds16(dV, Vb8 + (size_t)sr * (TKc * 2) + (size_t)(kt + 1) * 128 + sc * 16);
    }
    const char* sKb = sK + buf * 8192;
    const char* sVb = sV + buf * 8192;

    // QK^T: A = K[key=nf*16+l15][d], B = Q -> S^T[key][q=l15]  (log2 domain)
    f32x4 s[4] = {z, z, z, z};
#pragma unroll
    for (int nf = 0; nf < 4; ++nf) {
      const char* krow = sKb + (nf * 16 + l15) * 128;
      bf16x8 k0 = *reinterpret_cast<const bf16x8*>(krow + ((l4 ^ swz) << 4));
      bf16x8 k1 = *reinterpret_cast<const bf16x8*>(krow + (((4 + l4) ^ swz) << 4));
      s[nf] = MFMA16(k0, bq0, s[nf]);
      s[nf] = MFMA16(k1, bq1, s[nf]);
    }
    // V fragments from LDS: B[k=key][n=d]:  va[df][kk] = V^T tile row d
    bf16x8 va[4][2];
#pragma unroll
    for (int df = 0; df < 4; ++df) {
      const char* vrow = sVb + (df * 16 + l15) * 128;
      va[df][0] = *reinterpret_cast<const bf16x8*>(vrow + ((l4 ^ swz) << 4));
      va[df][1] = *reinterpret_cast<const bf16x8*>(vrow + (((4 + l4) ^ swz) << 4));
    }

    // ---- lane-local softmax (one q-row per lane, log2 domain) ----
    float pm = fmaxf(fmaxf(fmaxf(s[0][0], s[0][1]), fmaxf(s[0][2], s[0][3])),
                     fmaxf(fmaxf(s[1][0], s[1][1]), fmaxf(s[1][2], s[1][3])));
    pm = fmaxf(pm, fmaxf(fmaxf(fmaxf(s[2][0], s[2][1]), fmaxf(s[2][2], s[2][3])),
                         fmaxf(fmaxf(s[3][0], s[3][1]), fmaxf(s[3][2], s[3][3]))));
    pm = fmaxf(pm, __shfl_xor(pm, 16));
    pm = fmaxf(pm, __shfl_xor(pm, 32));
    if (!__all(pm - m <= 11.5f)) {  // T13 defer-max (log2 units)
      float mn = fmaxf(m, pm);
      float sc2 = exp2f(m - mn);
      m = mn;
      l *= sc2;
#pragma unroll
      for (int df = 0; df < 4; ++df) accO[df] *= sc2;
    }
    float ps = 0.f;
#pragma unroll
    for (int nf = 0; nf < 4; ++nf)
#pragma unroll
      for (int r = 0; r < 4; ++r) {
        float p = exp2f(s[nf][r] - m);
        s[nf][r] = p;
        ps += p;
      }
    ps += __shfl_xor(ps, 16);
    ps += __shfl_xor(ps, 32);
    l += ps;

    // ---- P -> per-wave LDS (row q=l15): 4x ds_write_b64, swizzled ----
#pragma unroll
    for (int nf = 0; nf < 4; ++nf) {
      bf16x4v pv;
      pv[0] = (__bf16)s[nf][0];
      pv[1] = (__bf16)s[nf][1];
      pv[2] = (__bf16)s[nf][2];
      pv[3] = (__bf16)s[nf][3];
      *reinterpret_cast<uint2*>(pb + l15 * 128 + ((nf * 32 + l4 * 8) ^ rx)) =
          __builtin_bit_cast(uint2, pv);
    }
    // ---- PV: A = P[q=l15][k=key], B = V^T[key][d] ----
    bf16x8 ap0 = *reinterpret_cast<const bf16x8*>(pb + l15 * 128 + ((l4 * 16) ^ rx));
    bf16x8 ap1 = *reinterpret_cast<const bf16x8*>(pb + l15 * 128 + ((64 + l4 * 16) ^ rx));
#pragma unroll
    for (int df = 0; df < 4; ++df)
      accO[df] = MFMA16(ap1, va[df][1], MFMA16(ap0, va[df][0], accO[df]));

    __syncthreads();  // drains vmcnt(0): next tile landed; all waves done reading
    buf ^= 1;
  }

  // epilogue: lane holds O[q=q0+l4*4+r][d=df*16+l15]; l lives at lane l4*4+r
  float inv[4];
#pragma unroll
  for (int r = 0; r < 4; ++r) inv[r] = 1.f / __shfl(l, l4 * 4 + r);
#pragma unroll
  for (int df = 0; df < 4; ++df)
#pragma unroll
    for (int r = 0; r < 4; ++r) {
      int row = q0 + l4 * 4 + r;
      int col = h * HDc + df * 16 + l15;
      Ob[((size_t)b * TQc + row) * Dc + col] = bfbits(accO[df][r] * inv[r]);
    }
}

// ---------------------------------------------------------------------------
extern "C" void kernel_launch(void* const* d_in, const int* in_sizes, int n_in,
                              void* d_out, int out_size, void* d_ws, size_t ws_size,
                              hipStream_t stream) {
  const float* X  = (const float*)d_in[0];
  const float* E  = (const float*)d_in[1];
  const float* Wq = (const float*)d_in[2];
  const float* bq = (const float*)d_in[3];
  const float* Wk = (const float*)d_in[4];
  const float* bk = (const float*)d_in[5];
  const float* Wv = (const float*)d_in[6];
  const float* bv = (const float*)d_in[7];
  const float* Wo = (const float*)d_in[8];
  const float* bo = (const float*)d_in[9];
  float* out = (float*)d_out;
  char* ws = (char*)d_ws;

  const size_t MB = 1ull << 20;
  if (ws_size < 42 * MB) return;  // tripwire: reproduces stub failure signature

  ushort* Xb   = (ushort*)(ws + 0 * MB);   // [4096][1024] bf16
  ushort* Eb   = (ushort*)(ws + 8 * MB);   // [4096][1024]
  ushort* Wqt  = (ushort*)(ws + 16 * MB);  // [1024][1024]
  ushort* Wkvt = (ushort*)(ws + 18 * MB);  // [512][1024] (Wk^T | Wv^T)
  ushort* Wot  = (ushort*)(ws + 19 * MB);  // [1024][1024]
  ushort* Qb   = (ushort*)(ws + 21 * MB);  // [2][16][2048][64]
  ushort* Kb   = (ushort*)(ws + 29 * MB);  // [2][4][2048][64]
  ushort* Vt   = (ushort*)(ws + 31 * MB);  // [2][4][64][2048]
  ushort* Ob   = (ushort*)(ws + 33 * MB);  // [2][2048][1024]

  // 1. casts + weight transposes
  prep_k<<<dim3(8960), 256, 0, stream>>>(X, E, Wq, Wo, Wk, Wv, Xb, Eb, Wqt, Wot, Wkvt);
  // 2. Q-proj (+RoPE+scale) and KV-proj (K+RoPE, V^T) concurrently
  qkv_k<<<dim3(768), 256, 0, stream>>>(Xb, Eb, Wqt, Wkvt, bq, bk, bv, Qb, Kb, Vt);
  // 3. attention -> Ob
  attn_k<<<dim3(512), dim3(512), 0, stream>>>(Qb, Kb, Vt, Ob);
  // 4. output projection -> out (f32)
  oproj_k<<<dim3(512), 256, 0, stream>>>(Ob, Wot, bo, out);
}

// Round 7
// 106.338 us; speedup vs baseline: 3.9273x; 1.1318x over previous
//
#include <hip/hip_runtime.h>
#include <cstdint>

// ---------------------------------------------------------------------------
// GQA cross-attention, bf16-MFMA pipeline (4 dispatches):
//   prep_k   : X,E -> bf16 casts ; Wq,Wo,Wk|Wv -> transposed bf16
//   qkv_k    : Q-proj (+RoPE, *0.125*log2e -> Qb) and KV-proj (K+RoPE -> Kb,
//              V -> transposed Vt) in ONE 768-block launch, 2-phase dbuf GEMM
//   attn_k   : flash attention, 8 waves x 16 q-rows (512 thr), log2 softmax
//              with RAW v_exp_f32 (libm exp2f costs ~10 ops; native is 1)
//   oproj_k  : O-projection, f32 out
// ---------------------------------------------------------------------------

typedef __bf16 bf16x8 __attribute__((ext_vector_type(8)));
typedef __bf16 bf16x4v __attribute__((ext_vector_type(4)));
typedef float f32x4 __attribute__((ext_vector_type(4)));

#define MFMA16(a, b, c) __builtin_amdgcn_mfma_f32_16x16x32_bf16((a), (b), (c), 0, 0, 0)

constexpr int Bc = 2, TQc = 2048, TKc = 2048, Dc = 1024, Hc = 16, Gc = 4, HDc = 64;
constexpr float QSCALE = 0.18033688011112042f;  // 0.125 * log2(e): log2-domain scores

__device__ __forceinline__ ushort bfbits(float x) {  // native RNE f32->bf16
  __bf16 h = (__bf16)x;
  return __builtin_bit_cast(ushort, h);
}

__device__ __forceinline__ float fexp2(float x) {  // raw v_exp_f32: D = 2^S0
  float r;
  asm("v_exp_f32 %0, %1" : "=v"(r) : "v"(x));
  return r;
}

__device__ __forceinline__ void async_lds16(void* lds, const void* g) {
  // wave-uniform LDS base; lane i lands at base + 16*i (guide §5)
  __builtin_amdgcn_global_load_lds((const __attribute__((address_space(1))) uint32_t*)g,
                                   (__attribute__((address_space(3))) uint32_t*)lds,
                                   16, 0, 0);
}

// ---------------- prep: casts (8192 blocks) + weight transposes (768) ------
__global__ __launch_bounds__(256) void prep_k(const float* __restrict__ X,
                                              const float* __restrict__ E,
                                              const float* __restrict__ Wq,
                                              const float* __restrict__ Wo,
                                              const float* __restrict__ Wk,
                                              const float* __restrict__ Wv,
                                              ushort* __restrict__ Xb,
                                              ushort* __restrict__ Eb,
                                              ushort* __restrict__ Wqt,
                                              ushort* __restrict__ Wot,
                                              ushort* __restrict__ Wkvt) {
  __shared__ float t[64][65];
  const int bid = blockIdx.x;
  if (bid < 8192) {  // cast: 4096 blocks X, 4096 blocks E
    const float* s = (bid < 4096) ? X : E;
    ushort* d = (bid < 4096) ? Xb : Eb;
    int i = (bid & 4095) * 256 + threadIdx.x;
    float4 v = reinterpret_cast<const float4*>(s)[i];
    ushort4 o;
    o.x = bfbits(v.x); o.y = bfbits(v.y); o.z = bfbits(v.z); o.w = bfbits(v.w);
    reinterpret_cast<ushort4*>(d)[i] = o;
    return;
  }
  // weight transpose: W[R][C] f32 -> Wt[C][R] bf16 (R = 1024 always)
  const int w = bid - 8192;           // [0, 768)
  const int z = w >> 8, rem = w & 255;
  const int bx = rem & 15, by = rem >> 4;
  const float* src;
  ushort* dst;
  int C, c0;
  if (z == 0)      { src = Wq; dst = Wqt; C = 1024; c0 = bx * 64; }
  else if (z == 1) { src = Wo; dst = Wot; C = 1024; c0 = bx * 64; }
  else {
    if (bx >= 8) return;
    if (bx < 4) { src = Wk; dst = Wkvt; }
    else        { src = Wv; dst = Wkvt + 256 * 1024; }
    C = 256; c0 = (bx & 3) * 64;
  }
  const int r0 = by * 64;
  const int tx = threadIdx.x & 63, ty = threadIdx.x >> 6;
#pragma unroll
  for (int i = 0; i < 16; ++i) {
    int r = i * 4 + ty;
    t[r][tx] = src[(size_t)(r0 + r) * C + c0 + tx];
  }
  __syncthreads();
#pragma unroll
  for (int i = 0; i < 16; ++i) {
    int c = i * 4 + ty;
    dst[(size_t)(c0 + c) * 1024 + r0 + tx] = bfbits(t[tx][c]);
  }
}

// ------- GEMM mainloop: 128x64 tile, BK=64, 2-phase double-buffered --------
// LDS XOR-swizzle (16B chunk ^= row&7): linear dest, pre-swizzled global
// source, swizzled ds_read (rule #21).  One barrier per K-step.
__device__ __forceinline__ void gemm_mainloop(const ushort* __restrict__ A,
                                              const ushort* __restrict__ Bt,
                                              int m0, int n0, int K,
                                              char* sA, char* sB,
                                              f32x4 acc[4][2]) {
  const int lane = threadIdx.x & 63, wid = threadIdx.x >> 6;
  const int l15 = lane & 15, l4 = lane >> 4;
  const int wr = (wid >> 1) * 64, wc = (wid & 1) * 32;
  const int srow = lane >> 3;                    // row within 8-row chunk
  const int scc = (lane & 7) ^ (srow & 7);       // pre-swizzled global chunk
  const int rxr = l15 & 7;                       // read-side row xor

  const int nsteps = K >> 6;
  // prologue: stage K-step 0 into buf 0
#pragma unroll
  for (int j = 0; j < 4; ++j) {
    int c = wid * 4 + j;
    async_lds16(sA + c * 1024, A + (size_t)(m0 + c * 8 + srow) * K + scc * 8);
  }
#pragma unroll
  for (int j = 0; j < 2; ++j) {
    int c = wid * 2 + j;
    async_lds16(sB + c * 1024, Bt + (size_t)(n0 + c * 8 + srow) * K + scc * 8);
  }
  __syncthreads();

  int buf = 0;
  for (int s2 = 0; s2 < nsteps; ++s2) {
    if (s2 + 1 < nsteps) {  // stage next step into the other buffer
      const int k0 = (s2 + 1) * 64;
      char* dA = sA + (buf ^ 1) * 16384;
      char* dB = sB + (buf ^ 1) * 8192;
#pragma unroll
      for (int j = 0; j < 4; ++j) {
        int c = wid * 4 + j;
        async_lds16(dA + c * 1024, A + (size_t)(m0 + c * 8 + srow) * K + k0 + scc * 8);
      }
#pragma unroll
      for (int j = 0; j < 2; ++j) {
        int c = wid * 2 + j;
        async_lds16(dB + c * 1024, Bt + (size_t)(n0 + c * 8 + srow) * K + k0 + scc * 8);
      }
    }
    const char* aB = sA + buf * 16384;
    const char* bB = sB + buf * 8192;
    bf16x8 af[2][4], bfr[2][2];
#pragma unroll
    for (int mi = 0; mi < 4; ++mi) {
      const int row = wr + mi * 16 + l15;
#pragma unroll
      for (int kk = 0; kk < 2; ++kk)
        af[kk][mi] = *reinterpret_cast<const bf16x8*>(
            aB + row * 128 + (((l4 + kk * 4) ^ rxr) << 4));
    }
#pragma unroll
    for (int ni = 0; ni < 2; ++ni) {
      const int row = wc + ni * 16 + l15;
#pragma unroll
      for (int kk = 0; kk < 2; ++kk)
        bfr[kk][ni] = *reinterpret_cast<const bf16x8*>(
            bB + row * 128 + (((l4 + kk * 4) ^ rxr) << 4));
    }
#pragma unroll
    for (int kk = 0; kk < 2; ++kk)
#pragma unroll
      for (int mi = 0; mi < 4; ++mi)
#pragma unroll
        for (int ni = 0; ni < 2; ++ni)
          acc[mi][ni] = MFMA16(af[kk][mi], bfr[kk][ni], acc[mi][ni]);
    __syncthreads();  // drains vmcnt(0): next tile landed; buf reads done
    buf ^= 1;
  }
}

// ------- shared GEMM epilogue.  mode 0: f32 C+bias. mode 1: Q+RoPE+scale.
// mode 2: N=512, col<256 K+RoPE; col>=256 V -> transposed Vt. --------------
__device__ __forceinline__ void gemm_epilogue(f32x4 acc[4][2], int mode, int m0,
                                              int n0, const float* b0,
                                              const float* b1, float* Cf,
                                              ushort* U0, ushort* U1, int N) {
  const int lane = threadIdx.x & 63, wid = threadIdx.x >> 6;
  const int l15 = lane & 15, l4 = lane >> 4;
  const int wr = (wid >> 1) * 64, wc = (wid & 1) * 32;
#pragma unroll
  for (int ni = 0; ni < 2; ++ni) {
    const int col = n0 + wc + ni * 16 + l15;
    if (mode == 0) {
      const float bv = b0[col];
#pragma unroll
      for (int mi = 0; mi < 4; ++mi) {
        const int rowb = m0 + wr + mi * 16 + l4 * 4;
#pragma unroll
        for (int r = 0; r < 4; ++r)
          Cf[(size_t)(rowb + r) * N + col] = acc[mi][ni][r] + bv;
      }
    } else if (mode == 1) {
      const int h = col >> 6, d = col & 63, fi = d >> 1, odd = d & 1;
      const float div = __expf(-0.28782313662425572f * (float)fi);  // -ln(1e4)/32
      const float bv = b0[col];
#pragma unroll
      for (int mi = 0; mi < 4; ++mi) {
        const int rowb = m0 + wr + mi * 16 + l4 * 4;
#pragma unroll
        for (int r = 0; r < 4; ++r) {
          const int row = rowb + r, b = row >> 11, t = row & 2047;
          const float val = acc[mi][ni][r] + bv;
          const float prt = __shfl_xor(val, 1);  // partner column (d^1)
          float sn, cs;
          __sincosf((float)t * div, &sn, &cs);
          const float o = odd ? (prt * sn + val * cs) : (val * cs - prt * sn);
          U0[(((size_t)(b * Hc + h)) * TQc + t) * HDc + d] = bfbits(o * QSCALE);
        }
      }
    } else {
      if (col < 256) {  // K path: RoPE -> Kb[b][g][t][d]
        const int g = col >> 6, d = col & 63, fi = d >> 1, odd = d & 1;
        const float div = __expf(-0.28782313662425572f * (float)fi);
        const float bv = b0[col];
#pragma unroll
        for (int mi = 0; mi < 4; ++mi) {
          const int rowb = m0 + wr + mi * 16 + l4 * 4;
#pragma unroll
          for (int r = 0; r < 4; ++r) {
            const int row = rowb + r, b = row >> 11, t = row & 2047;
            const float val = acc[mi][ni][r] + bv;
            const float prt = __shfl_xor(val, 1);
            float sn, cs;
            __sincosf((float)t * div, &sn, &cs);
            const float o = odd ? (prt * sn + val * cs) : (val * cs - prt * sn);
            U0[(((size_t)(b * Gc + g)) * TKc + t) * HDc + d] = bfbits(o);
          }
        }
      } else {  // V path: transpose-write Vt[b][g][d][t]
        const int c2 = col - 256;
        const int g = c2 >> 6, d = c2 & 63;
        const float bv = b1[c2];
#pragma unroll
        for (int mi = 0; mi < 4; ++mi) {
          const int rowb = m0 + wr + mi * 16 + l4 * 4;
          const int b = rowb >> 11, t0 = rowb & 2047;
          ushort4 w;
          w.x = bfbits(acc[mi][ni][0] + bv);
          w.y = bfbits(acc[mi][ni][1] + bv);
          w.z = bfbits(acc[mi][ni][2] + bv);
          w.w = bfbits(acc[mi][ni][3] + bv);
          *reinterpret_cast<ushort4*>(
              &U1[(((size_t)(b * Gc + g)) * HDc + d) * TKc + t0]) = w;
        }
      }
    }
  }
}

// ------- Q-proj (blocks 0..511) + KV-proj (512..767), one launch -----------
__global__ __launch_bounds__(256) void qkv_k(const ushort* __restrict__ Xb,
                                             const ushort* __restrict__ Eb,
                                             const ushort* __restrict__ Wqt,
                                             const ushort* __restrict__ Wkvt,
                                             const float* __restrict__ bq,
                                             const float* __restrict__ bk,
                                             const float* __restrict__ bv,
                                             ushort* __restrict__ Qb,
                                             ushort* __restrict__ Kb,
                                             ushort* __restrict__ Vt) {
  __shared__ __attribute__((aligned(16))) char smem[48 * 1024];
  const int bid = blockIdx.x;
  const ushort *A, *Bt;
  const float *b0, *b1 = nullptr;
  ushort *U0, *U1 = nullptr;
  int mode, tb, tn;
  if (bid < 512) { A = Xb; Bt = Wqt; b0 = bq; U0 = Qb; mode = 1; tb = bid; tn = 16; }
  else { A = Eb; Bt = Wkvt; b0 = bk; b1 = bv; U0 = Kb; U1 = Vt; mode = 2; tb = bid - 512; tn = 8; }
  const int m0 = (tb / tn) * 128, n0 = (tb % tn) * 64;
  const f32x4 z = {0.f, 0.f, 0.f, 0.f};
  f32x4 acc[4][2] = {{z, z}, {z, z}, {z, z}, {z, z}};
  gemm_mainloop(A, Bt, m0, n0, 1024, smem, smem + 32768, acc);
  gemm_epilogue(acc, mode, m0, n0, b0, b1, nullptr, U0, U1, 0);
}

// ------- O-projection: out = Ob * Wot^T + bo (f32) -------------------------
__global__ __launch_bounds__(256) void oproj_k(const ushort* __restrict__ Ob,
                                               const ushort* __restrict__ Wot,
                                               const float* __restrict__ bo,
                                               float* __restrict__ out) {
  __shared__ __attribute__((aligned(16))) char smem[48 * 1024];
  const int bid = blockIdx.x;
  const int m0 = (bid >> 4) * 128, n0 = (bid & 15) * 64;
  const f32x4 z = {0.f, 0.f, 0.f, 0.f};
  f32x4 acc[4][2] = {{z, z}, {z, z}, {z, z}, {z, z}};
  gemm_mainloop(Ob, Wot, m0, n0, 1024, smem, smem + 32768, acc);
  gemm_epilogue(acc, 0, m0, n0, bo, nullptr, out, nullptr, nullptr, 1024);
}

// ------- flash attention, LDS-staged K/V, swapped-QK^T, log2 softmax -------
// Qb[b][h][t][64] (pre-scaled by 0.125*log2e), Kb[b][g][t][64], Vt[b][g][64][t].
// 512 thr = 8 waves x 16 q-rows (QBLK=128), KVBLK=64, double-buffered LDS.
// K/V tiles: 64 rows x 128B, XOR-swizzled (chunk ^= row&7): linear LDS dest,
// pre-swizzled per-lane GLOBAL source, swizzled ds_read (rule #21).
__global__ __launch_bounds__(512, 4) void attn_k(const ushort* __restrict__ Qg,
                                                 const ushort* __restrict__ Kg,
                                                 const ushort* __restrict__ Vg,
                                                 ushort* __restrict__ Ob) {
  __shared__ __attribute__((aligned(16))) char smem[48 * 1024];
  const int lane = threadIdx.x & 63, wid = threadIdx.x >> 6;
  const int l15 = lane & 15, l4 = lane >> 4;
  // XCD-aware decode: bid&7 = (b,g) group -> each XCD L2 caches ONE group's K/V
  const int bid = blockIdx.x;  // 512 blocks
  const int bg = bid & 7, pos = bid >> 3;
  const int b = bg >> 2, g = bg & 3;
  const int h = g * 4 + (pos >> 4);
  const int q0 = (pos & 15) * 128 + wid * 16;
  const ushort* Qp = Qg + ((size_t)(b * Hc + h)) * TQc * HDc;
  const ushort* Kp = Kg + ((size_t)(b * Gc + g)) * TKc * HDc;
  const ushort* Vp = Vg + ((size_t)(b * Gc + g)) * HDc * TKc;
  char* sK = smem;                         // [2][8192]
  char* sV = smem + 16384;                 // [2][8192]
  char* pb = smem + 32768 + wid * 2048;    // per-wave P tile [16][64] bf16
  const int rx = (l15 & 7) << 4;           // P-row swizzle
  const int swz = l15 & 7;                 // K/V fragment chunk swizzle

  // staging geometry: wave stages 1KB of K and 1KB of V per tile
  const int sr = wid * 8 + (lane >> 3);              // tile row this lane fills
  const int sc = (lane & 7) ^ ((lane >> 3) & 7);     // pre-swizzled src chunk
  const char* Kb8 = (const char*)Kp;
  const char* Vb8 = (const char*)Vp;

  // Q (B operand): col n=l15 -> q=q0+l15, k=l4*8+j -> d
  bf16x8 bq0 = *reinterpret_cast<const bf16x8*>(Qp + (size_t)(q0 + l15) * HDc + l4 * 8);
  bf16x8 bq1 = *reinterpret_cast<const bf16x8*>(Qp + (size_t)(q0 + l15) * HDc + 32 + l4 * 8);

  float m = -INFINITY, l = 0.f;
  const f32x4 z = {0.f, 0.f, 0.f, 0.f};
  f32x4 accO[4] = {z, z, z, z};

  constexpr int NT = TKc / 64;
  // prologue: stage tile 0 into buffer 0
  async_lds16(sK + wid * 1024, Kb8 + (size_t)sr * 128 + sc * 16);
  async_lds16(sV + wid * 1024, Vb8 + (size_t)sr * (TKc * 2) + sc * 16);
  __syncthreads();

  int buf = 0;
  for (int kt = 0; kt < NT; ++kt) {
    if (kt + 1 < NT) {  // issue next-tile loads; they complete under compute
      char* dK = sK + (buf ^ 1) * 8192 + wid * 1024;
      char* dV = sV + (buf ^ 1) * 8192 + wid * 1024;
      async_lds16(dK, Kb8 + ((size_t)(kt + 1) * 64 + sr) * 128 + sc * 16);
      async_lds16(dV, Vb8 + (size_t)sr * (TKc * 2) + (size_t)(kt + 1) * 128 + sc * 16);
    }
    const char* sKb = sK + buf * 8192;
    const char* sVb = sV + buf * 8192;

    // QK^T: A = K[key=nf*16+l15][d], B = Q -> S^T[key][q=l15]  (log2 domain)
    f32x4 s[4] = {z, z, z, z};
#pragma unroll
    for (int nf = 0; nf < 4; ++nf) {
      const char* krow = sKb + (nf * 16 + l15) * 128;
      bf16x8 k0 = *reinterpret_cast<const bf16x8*>(krow + ((l4 ^ swz) << 4));
      bf16x8 k1 = *reinterpret_cast<const bf16x8*>(krow + (((4 + l4) ^ swz) << 4));
      s[nf] = MFMA16(k0, bq0, s[nf]);
      s[nf] = MFMA16(k1, bq1, s[nf]);
    }
    // V fragments from LDS: B[k=key][n=d]:  va[df][kk] = V^T tile row d
    bf16x8 va[4][2];
#pragma unroll
    for (int df = 0; df < 4; ++df) {
      const char* vrow = sVb + (df * 16 + l15) * 128;
      va[df][0] = *reinterpret_cast<const bf16x8*>(vrow + ((l4 ^ swz) << 4));
      va[df][1] = *reinterpret_cast<const bf16x8*>(vrow + (((4 + l4) ^ swz) << 4));
    }

    // ---- lane-local softmax (one q-row per lane, log2 domain) ----
    float pm = fmaxf(fmaxf(fmaxf(s[0][0], s[0][1]), fmaxf(s[0][2], s[0][3])),
                     fmaxf(fmaxf(s[1][0], s[1][1]), fmaxf(s[1][2], s[1][3])));
    pm = fmaxf(pm, fmaxf(fmaxf(fmaxf(s[2][0], s[2][1]), fmaxf(s[2][2], s[2][3])),
                         fmaxf(fmaxf(s[3][0], s[3][1]), fmaxf(s[3][2], s[3][3]))));
    pm = fmaxf(pm, __shfl_xor(pm, 16));
    pm = fmaxf(pm, __shfl_xor(pm, 32));
    if (!__all(pm - m <= 11.5f)) {  // T13 defer-max (log2 units)
      float mn = fmaxf(m, pm);
      float sc2 = fexp2(m - mn);
      m = mn;
      l *= sc2;
#pragma unroll
      for (int df = 0; df < 4; ++df) accO[df] *= sc2;
    }
    float ps = 0.f;
#pragma unroll
    for (int nf = 0; nf < 4; ++nf)
#pragma unroll
      for (int r = 0; r < 4; ++r) {
        float p = fexp2(s[nf][r] - m);
        s[nf][r] = p;
        ps += p;
      }
    ps += __shfl_xor(ps, 16);
    ps += __shfl_xor(ps, 32);
    l += ps;

    // ---- P -> per-wave LDS (row q=l15): 4x ds_write_b64, swizzled ----
#pragma unroll
    for (int nf = 0; nf < 4; ++nf) {
      bf16x4v pv;
      pv[0] = (__bf16)s[nf][0];
      pv[1] = (__bf16)s[nf][1];
      pv[2] = (__bf16)s[nf][2];
      pv[3] = (__bf16)s[nf][3];
      *reinterpret_cast<uint2*>(pb + l15 * 128 + ((nf * 32 + l4 * 8) ^ rx)) =
          __builtin_bit_cast(uint2, pv);
    }
    // ---- PV: A = P[q=l15][k=key], B = V^T[key][d] ----
    bf16x8 ap0 = *reinterpret_cast<const bf16x8*>(pb + l15 * 128 + ((l4 * 16) ^ rx));
    bf16x8 ap1 = *reinterpret_cast<const bf16x8*>(pb + l15 * 128 + ((64 + l4 * 16) ^ rx));
#pragma unroll
    for (int df = 0; df < 4; ++df)
      accO[df] = MFMA16(ap1, va[df][1], MFMA16(ap0, va[df][0], accO[df]));

    __syncthreads();  // drains vmcnt(0): next tile landed; all waves done reading
    buf ^= 1;
  }

  // epilogue: lane holds O[q=q0+l4*4+r][d=df*16+l15]; l lives at lane l4*4+r
  float inv[4];
#pragma unroll
  for (int r = 0; r < 4; ++r) inv[r] = 1.f / __shfl(l, l4 * 4 + r);
#pragma unroll
  for (int df = 0; df < 4; ++df)
#pragma unroll
    for (int r = 0; r < 4; ++r) {
      int row = q0 + l4 * 4 + r;
      int col = h * HDc + df * 16 + l15;
      Ob[((size_t)b * TQc + row) * Dc + col] = bfbits(accO[df][r] * inv[r]);
    }
}

// ---------------------------------------------------------------------------
extern "C" void kernel_launch(void* const* d_in, const int* in_sizes, int n_in,
                              void* d_out, int out_size, void* d_ws, size_t ws_size,
                              hipStream_t stream) {
  const float* X  = (const float*)d_in[0];
  const float* E  = (const float*)d_in[1];
  const float* Wq = (const float*)d_in[2];
  const float* bq = (const float*)d_in[3];
  const float* Wk = (const float*)d_in[4];
  const float* bk = (const float*)d_in[5];
  const float* Wv = (const float*)d_in[6];
  const float* bv = (const float*)d_in[7];
  const float* Wo = (const float*)d_in[8];
  const float* bo = (const float*)d_in[9];
  float* out = (float*)d_out;
  char* ws = (char*)d_ws;

  const size_t MB = 1ull << 20;
  if (ws_size < 42 * MB) return;  // tripwire: reproduces stub failure signature

  ushort* Xb   = (ushort*)(ws + 0 * MB);   // [4096][1024] bf16
  ushort* Eb   = (ushort*)(ws + 8 * MB);   // [4096][1024]
  ushort* Wqt  = (ushort*)(ws + 16 * MB);  // [1024][1024]
  ushort* Wkvt = (ushort*)(ws + 18 * MB);  // [512][1024] (Wk^T | Wv^T)
  ushort* Wot  = (ushort*)(ws + 19 * MB);  // [1024][1024]
  ushort* Qb   = (ushort*)(ws + 21 * MB);  // [2][16][2048][64]
  ushort* Kb   = (ushort*)(ws + 29 * MB);  // [2][4][2048][64]
  ushort* Vt   = (ushort*)(ws + 31 * MB);  // [2][4][64][2048]
  ushort* Ob   = (ushort*)(ws + 33 * MB);  // [2][2048][1024]

  // 1. casts + weight transposes
  prep_k<<<dim3(8960), 256, 0, stream>>>(X, E, Wq, Wo, Wk, Wv, Xb, Eb, Wqt, Wot, Wkvt);
  // 2. Q-proj (+RoPE+scale) and KV-proj (K+RoPE, V^T) concurrently
  qkv_k<<<dim3(768), 256, 0, stream>>>(Xb, Eb, Wqt, Wkvt, bq, bk, bv, Qb, Kb, Vt);
  // 3. attention -> Ob
  attn_k<<<dim3(512), dim3(512), 0, stream>>>(Qb, Kb, Vt, Ob);
  // 4. output projection -> out (f32)
  oproj_k<<<dim3(512), 256, 0, stream>>>(Ob, Wot, bo, out);
}

// Round 10
// 105.153 us; speedup vs baseline: 3.9715x; 1.0113x over previous
//
#include <hip/hip_runtime.h>
#include <cstdint>

// ---------------------------------------------------------------------------
// GQA cross-attention, bf16-MFMA pipeline (4 dispatches):
//   prep_k   : X,E -> bf16 casts ; Wq,Wo,Wk|Wv -> transposed bf16
//   qkv_k    : Q-proj (+RoPE, *0.125*log2e -> Qb) and KV-proj (K+RoPE -> Kb,
//              V -> transposed Vt) in ONE 768-block launch, 2-phase dbuf GEMM
//   attn_k   : flash attention, 8 waves x 16 q-rows (512 thr), log2 softmax
//              (running max + defer-max, raw v_exp_f32). NOTE: the no-max
//              variant (rounds 8/9) failed with ~0.3 absmax for reasons not
//              identifiable from source — do NOT retry without disasm.
//   oproj_k  : O-projection, f32 out
// ---------------------------------------------------------------------------

typedef __bf16 bf16x8 __attribute__((ext_vector_type(8)));
typedef __bf16 bf16x4v __attribute__((ext_vector_type(4)));
typedef float f32x4 __attribute__((ext_vector_type(4)));

#define MFMA16(a, b, c) __builtin_amdgcn_mfma_f32_16x16x32_bf16((a), (b), (c), 0, 0, 0)

constexpr int Bc = 2, TQc = 2048, TKc = 2048, Dc = 1024, Hc = 16, Gc = 4, HDc = 64;
constexpr float QSCALE = 0.18033688011112042f;  // 0.125 * log2(e): log2-domain scores

__device__ __forceinline__ ushort bfbits(float x) {  // native RNE f32->bf16
  __bf16 h = (__bf16)x;
  return __builtin_bit_cast(ushort, h);
}

__device__ __forceinline__ float fexp2(float x) {  // raw v_exp_f32: D = 2^S0
  float r;
  asm("v_exp_f32 %0, %1" : "=v"(r) : "v"(x));
  return r;
}

__device__ __forceinline__ float fmax3(float a, float b, float c) {
  return fmaxf(fmaxf(a, b), c);  // clang fuses to v_max3_f32 on gfx9+
}

__device__ __forceinline__ void async_lds16(void* lds, const void* g) {
  // wave-uniform LDS base; lane i lands at base + 16*i (guide §5)
  __builtin_amdgcn_global_load_lds((const __attribute__((address_space(1))) uint32_t*)g,
                                   (__attribute__((address_space(3))) uint32_t*)lds,
                                   16, 0, 0);
}

// ---------------- prep: casts (8192 blocks) + weight transposes (768) ------
__global__ __launch_bounds__(256) void prep_k(const float* __restrict__ X,
                                              const float* __restrict__ E,
                                              const float* __restrict__ Wq,
                                              const float* __restrict__ Wo,
                                              const float* __restrict__ Wk,
                                              const float* __restrict__ Wv,
                                              ushort* __restrict__ Xb,
                                              ushort* __restrict__ Eb,
                                              ushort* __restrict__ Wqt,
                                              ushort* __restrict__ Wot,
                                              ushort* __restrict__ Wkvt) {
  __shared__ float t[64][65];
  const int bid = blockIdx.x;
  if (bid < 8192) {  // cast: 4096 blocks X, 4096 blocks E
    const float* s = (bid < 4096) ? X : E;
    ushort* d = (bid < 4096) ? Xb : Eb;
    int i = (bid & 4095) * 256 + threadIdx.x;
    float4 v = reinterpret_cast<const float4*>(s)[i];
    ushort4 o;
    o.x = bfbits(v.x); o.y = bfbits(v.y); o.z = bfbits(v.z); o.w = bfbits(v.w);
    reinterpret_cast<ushort4*>(d)[i] = o;
    return;
  }
  // weight transpose: W[R][C] f32 -> Wt[C][R] bf16 (R = 1024 always)
  const int w = bid - 8192;           // [0, 768)
  const int z = w >> 8, rem = w & 255;
  const int bx = rem & 15, by = rem >> 4;
  const float* src;
  ushort* dst;
  int C, c0;
  if (z == 0)      { src = Wq; dst = Wqt; C = 1024; c0 = bx * 64; }
  else if (z == 1) { src = Wo; dst = Wot; C = 1024; c0 = bx * 64; }
  else {
    if (bx >= 8) return;
    if (bx < 4) { src = Wk; dst = Wkvt; }
    else        { src = Wv; dst = Wkvt + 256 * 1024; }
    C = 256; c0 = (bx & 3) * 64;
  }
  const int r0 = by * 64;
  const int tx = threadIdx.x & 63, ty = threadIdx.x >> 6;
#pragma unroll
  for (int i = 0; i < 16; ++i) {
    int r = i * 4 + ty;
    t[r][tx] = src[(size_t)(r0 + r) * C + c0 + tx];
  }
  __syncthreads();
#pragma unroll
  for (int i = 0; i < 16; ++i) {
    int c = i * 4 + ty;
    dst[(size_t)(c0 + c) * 1024 + r0 + tx] = bfbits(t[tx][c]);
  }
}

// ------- GEMM mainloop: 128x64 tile, BK=64, 2-phase double-buffered --------
// LDS XOR-swizzle (16B chunk ^= row&7): linear dest, pre-swizzled global
// source, swizzled ds_read (rule #21).  One barrier per K-step.
__device__ __forceinline__ void gemm_mainloop(const ushort* __restrict__ A,
                                              const ushort* __restrict__ Bt,
                                              int m0, int n0, int K,
                                              char* sA, char* sB,
                                              f32x4 acc[4][2]) {
  const int lane = threadIdx.x & 63, wid = threadIdx.x >> 6;
  const int l15 = lane & 15, l4 = lane >> 4;
  const int wr = (wid >> 1) * 64, wc = (wid & 1) * 32;
  const int srow = lane >> 3;                    // row within 8-row chunk
  const int scc = (lane & 7) ^ (srow & 7);       // pre-swizzled global chunk
  const int rxr = l15 & 7;                       // read-side row xor

  const int nsteps = K >> 6;
  // prologue: stage K-step 0 into buf 0
#pragma unroll
  for (int j = 0; j < 4; ++j) {
    int c = wid * 4 + j;
    async_lds16(sA + c * 1024, A + (size_t)(m0 + c * 8 + srow) * K + scc * 8);
  }
#pragma unroll
  for (int j = 0; j < 2; ++j) {
    int c = wid * 2 + j;
    async_lds16(sB + c * 1024, Bt + (size_t)(n0 + c * 8 + srow) * K + scc * 8);
  }
  __syncthreads();

  int buf = 0;
  for (int s2 = 0; s2 < nsteps; ++s2) {
    if (s2 + 1 < nsteps) {  // stage next step into the other buffer
      const int k0 = (s2 + 1) * 64;
      char* dA = sA + (buf ^ 1) * 16384;
      char* dB = sB + (buf ^ 1) * 8192;
#pragma unroll
      for (int j = 0; j < 4; ++j) {
        int c = wid * 4 + j;
        async_lds16(dA + c * 1024, A + (size_t)(m0 + c * 8 + srow) * K + k0 + scc * 8);
      }
#pragma unroll
      for (int j = 0; j < 2; ++j) {
        int c = wid * 2 + j;
        async_lds16(dB + c * 1024, Bt + (size_t)(n0 + c * 8 + srow) * K + k0 + scc * 8);
      }
    }
    const char* aB = sA + buf * 16384;
    const char* bB = sB + buf * 8192;
    bf16x8 af[2][4], bfr[2][2];
#pragma unroll
    for (int mi = 0; mi < 4; ++mi) {
      const int row = wr + mi * 16 + l15;
#pragma unroll
      for (int kk = 0; kk < 2; ++kk)
        af[kk][mi] = *reinterpret_cast<const bf16x8*>(
            aB + row * 128 + (((l4 + kk * 4) ^ rxr) << 4));
    }
#pragma unroll
    for (int ni = 0; ni < 2; ++ni) {
      const int row = wc + ni * 16 + l15;
#pragma unroll
      for (int kk = 0; kk < 2; ++kk)
        bfr[kk][ni] = *reinterpret_cast<const bf16x8*>(
            bB + row * 128 + (((l4 + kk * 4) ^ rxr) << 4));
    }
#pragma unroll
    for (int kk = 0; kk < 2; ++kk)
#pragma unroll
      for (int mi = 0; mi < 4; ++mi)
#pragma unroll
        for (int ni = 0; ni < 2; ++ni)
          acc[mi][ni] = MFMA16(af[kk][mi], bfr[kk][ni], acc[mi][ni]);
    __syncthreads();  // drains vmcnt(0): next tile landed; buf reads done
    buf ^= 1;
  }
}

// ------- shared GEMM epilogue.  mode 0: f32 C+bias. mode 1: Q+RoPE+scale.
// mode 2: N=512, col<256 K+RoPE; col>=256 V -> transposed Vt. --------------
__device__ __forceinline__ void gemm_epilogue(f32x4 acc[4][2], int mode, int m0,
                                              int n0, const float* b0,
                                              const float* b1, float* Cf,
                                              ushort* U0, ushort* U1, int N) {
  const int lane = threadIdx.x & 63, wid = threadIdx.x >> 6;
  const int l15 = lane & 15, l4 = lane >> 4;
  const int wr = (wid >> 1) * 64, wc = (wid & 1) * 32;
#pragma unroll
  for (int ni = 0; ni < 2; ++ni) {
    const int col = n0 + wc + ni * 16 + l15;
    if (mode == 0) {
      const float bv = b0[col];
#pragma unroll
      for (int mi = 0; mi < 4; ++mi) {
        const int rowb = m0 + wr + mi * 16 + l4 * 4;
#pragma unroll
        for (int r = 0; r < 4; ++r)
          Cf[(size_t)(rowb + r) * N + col] = acc[mi][ni][r] + bv;
      }
    } else if (mode == 1) {
      const int h = col >> 6, d = col & 63, fi = d >> 1, odd = d & 1;
      const float div = __expf(-0.28782313662425572f * (float)fi);  // -ln(1e4)/32
      const float bv = b0[col];
#pragma unroll
      for (int mi = 0; mi < 4; ++mi) {
        const int rowb = m0 + wr + mi * 16 + l4 * 4;
#pragma unroll
        for (int r = 0; r < 4; ++r) {
          const int row = rowb + r, b = row >> 11, t = row & 2047;
          const float val = acc[mi][ni][r] + bv;
          const float prt = __shfl_xor(val, 1);  // partner column (d^1)
          float sn, cs;
          __sincosf((float)t * div, &sn, &cs);
          const float o = odd ? (prt * sn + val * cs) : (val * cs - prt * sn);
          U0[(((size_t)(b * Hc + h)) * TQc + t) * HDc + d] = bfbits(o * QSCALE);
        }
      }
    } else {
      if (col < 256) {  // K path: RoPE -> Kb[b][g][t][d]
        const int g = col >> 6, d = col & 63, fi = d >> 1, odd = d & 1;
        const float div = __expf(-0.28782313662425572f * (float)fi);
        const float bv = b0[col];
#pragma unroll
        for (int mi = 0; mi < 4; ++mi) {
          const int rowb = m0 + wr + mi * 16 + l4 * 4;
#pragma unroll
          for (int r = 0; r < 4; ++r) {
            const int row = rowb + r, b = row >> 11, t = row & 2047;
            const float val = acc[mi][ni][r] + bv;
            const float prt = __shfl_xor(val, 1);
            float sn, cs;
            __sincosf((float)t * div, &sn, &cs);
            const float o = odd ? (prt * sn + val * cs) : (val * cs - prt * sn);
            U0[(((size_t)(b * Gc + g)) * TKc + t) * HDc + d] = bfbits(o);
          }
        }
      } else {  // V path: transpose-write Vt[b][g][d][t]
        const int c2 = col - 256;
        const int g = c2 >> 6, d = c2 & 63;
        const float bv = b1[c2];
#pragma unroll
        for (int mi = 0; mi < 4; ++mi) {
          const int rowb = m0 + wr + mi * 16 + l4 * 4;
          const int b = rowb >> 11, t0 = rowb & 2047;
          ushort4 w;
          w.x = bfbits(acc[mi][ni][0] + bv);
          w.y = bfbits(acc[mi][ni][1] + bv);
          w.z = bfbits(acc[mi][ni][2] + bv);
          w.w = bfbits(acc[mi][ni][3] + bv);
          *reinterpret_cast<ushort4*>(
              &U1[(((size_t)(b * Gc + g)) * HDc + d) * TKc + t0]) = w;
        }
      }
    }
  }
}

// ------- Q-proj (blocks 0..511) + KV-proj (512..767), one launch -----------
__global__ __launch_bounds__(256) void qkv_k(const ushort* __restrict__ Xb,
                                             const ushort* __restrict__ Eb,
                                             const ushort* __restrict__ Wqt,
                                             const ushort* __restrict__ Wkvt,
                                             const float* __restrict__ bq,
                                             const float* __restrict__ bk,
                                             const float* __restrict__ bv,
                                             ushort* __restrict__ Qb,
                                             ushort* __restrict__ Kb,
                                             ushort* __restrict__ Vt) {
  __shared__ __attribute__((aligned(16))) char smem[48 * 1024];
  const int bid = blockIdx.x;
  const ushort *A, *Bt;
  const float *b0, *b1 = nullptr;
  ushort *U0, *U1 = nullptr;
  int mode, tb, tn;
  if (bid < 512) { A = Xb; Bt = Wqt; b0 = bq; U0 = Qb; mode = 1; tb = bid; tn = 16; }
  else { A = Eb; Bt = Wkvt; b0 = bk; b1 = bv; U0 = Kb; U1 = Vt; mode = 2; tb = bid - 512; tn = 8; }
  const int m0 = (tb / tn) * 128, n0 = (tb % tn) * 64;
  const f32x4 z = {0.f, 0.f, 0.f, 0.f};
  f32x4 acc[4][2] = {{z, z}, {z, z}, {z, z}, {z, z}};
  gemm_mainloop(A, Bt, m0, n0, 1024, smem, smem + 32768, acc);
  gemm_epilogue(acc, mode, m0, n0, b0, b1, nullptr, U0, U1, 0);
}

// ------- O-projection: out = Ob * Wot^T + bo (f32) -------------------------
__global__ __launch_bounds__(256) void oproj_k(const ushort* __restrict__ Ob,
                                               const ushort* __restrict__ Wot,
                                               const float* __restrict__ bo,
                                               float* __restrict__ out) {
  __shared__ __attribute__((aligned(16))) char smem[48 * 1024];
  const int bid = blockIdx.x;
  const int m0 = (bid >> 4) * 128, n0 = (bid & 15) * 64;
  const f32x4 z = {0.f, 0.f, 0.f, 0.f};
  f32x4 acc[4][2] = {{z, z}, {z, z}, {z, z}, {z, z}};
  gemm_mainloop(Ob, Wot, m0, n0, 1024, smem, smem + 32768, acc);
  gemm_epilogue(acc, 0, m0, n0, bo, nullptr, out, nullptr, nullptr, 1024);
}

// ------- flash attention, LDS-staged K/V, swapped-QK^T, log2 softmax -------
// Qb[b][h][t][64] (pre-scaled by 0.125*log2e), Kb[b][g][t][64], Vt[b][g][64][t].
// 512 thr = 8 waves x 16 q-rows (QBLK=128), KVBLK=64, double-buffered LDS.
// K/V tiles: 64 rows x 128B, XOR-swizzled (chunk ^= row&7): linear LDS dest,
// pre-swizzled per-lane GLOBAL source, swizzled ds_read (rule #21).
__global__ __launch_bounds__(512, 4) void attn_k(const ushort* __restrict__ Qg,
                                                 const ushort* __restrict__ Kg,
                                                 const ushort* __restrict__ Vg,
                                                 ushort* __restrict__ Ob) {
  __shared__ __attribute__((aligned(16))) char smem[48 * 1024];
  const int lane = threadIdx.x & 63, wid = threadIdx.x >> 6;
  const int l15 = lane & 15, l4 = lane >> 4;
  // XCD-aware decode: bid&7 = (b,g) group -> each XCD L2 caches ONE group's K/V
  const int bid = blockIdx.x;  // 512 blocks
  const int bg = bid & 7, pos = bid >> 3;
  const int b = bg >> 2, g = bg & 3;
  const int h = g * 4 + (pos >> 4);
  const int q0 = (pos & 15) * 128 + wid * 16;
  const ushort* Qp = Qg + ((size_t)(b * Hc + h)) * TQc * HDc;
  const ushort* Kp = Kg + ((size_t)(b * Gc + g)) * TKc * HDc;
  const ushort* Vp = Vg + ((size_t)(b * Gc + g)) * HDc * TKc;
  char* sK = smem;                         // [2][8192]
  char* sV = smem + 16384;                 // [2][8192]
  char* pb = smem + 32768 + wid * 2048;    // per-wave P tile [16][64] bf16
  const int rx = (l15 & 7) << 4;           // P-row swizzle
  const int swz = l15 & 7;                 // K/V fragment chunk swizzle

  // staging geometry: wave stages 1KB of K and 1KB of V per tile
  const int sr = wid * 8 + (lane >> 3);              // tile row this lane fills
  const int sc = (lane & 7) ^ ((lane >> 3) & 7);     // pre-swizzled src chunk
  const char* Kb8 = (const char*)Kp;
  const char* Vb8 = (const char*)Vp;

  // Q (B operand): col n=l15 -> q=q0+l15, k=l4*8+j -> d
  bf16x8 bq0 = *reinterpret_cast<const bf16x8*>(Qp + (size_t)(q0 + l15) * HDc + l4 * 8);
  bf16x8 bq1 = *reinterpret_cast<const bf16x8*>(Qp + (size_t)(q0 + l15) * HDc + 32 + l4 * 8);

  float m = -INFINITY, l = 0.f;
  const f32x4 z = {0.f, 0.f, 0.f, 0.f};
  f32x4 accO[4] = {z, z, z, z};

  constexpr int NT = TKc / 64;
  // prologue: stage tile 0 into buffer 0
  async_lds16(sK + wid * 1024, Kb8 + (size_t)sr * 128 + sc * 16);
  async_lds16(sV + wid * 1024, Vb8 + (size_t)sr * (TKc * 2) + sc * 16);
  __syncthreads();

  int buf = 0;
  for (int kt = 0; kt < NT; ++kt) {
    if (kt + 1 < NT) {  // issue next-tile loads; they complete under compute
      char* dK = sK + (buf ^ 1) * 8192 + wid * 1024;
      char* dV = sV + (buf ^ 1) * 8192 + wid * 1024;
      async_lds16(dK, Kb8 + ((size_t)(kt + 1) * 64 + sr) * 128 + sc * 16);
      async_lds16(dV, Vb8 + (size_t)sr * (TKc * 2) + (size_t)(kt + 1) * 128 + sc * 16);
    }
    const char* sKb = sK + buf * 8192;
    const char* sVb = sV + buf * 8192;

    // QK^T: A = K[key=nf*16+l15][d], B = Q -> S^T[key][q=l15]  (log2 domain)
    f32x4 s[4] = {z, z, z, z};
#pragma unroll
    for (int nf = 0; nf < 4; ++nf) {
      const char* krow = sKb + (nf * 16 + l15) * 128;
      bf16x8 k0 = *reinterpret_cast<const bf16x8*>(krow + ((l4 ^ swz) << 4));
      bf16x8 k1 = *reinterpret_cast<const bf16x8*>(krow + (((4 + l4) ^ swz) << 4));
      s[nf] = MFMA16(k0, bq0, s[nf]);
      s[nf] = MFMA16(k1, bq1, s[nf]);
    }
    // V fragments from LDS: B[k=key][n=d]:  va[df][kk] = V^T tile row d
    bf16x8 va[4][2];
#pragma unroll
    for (int df = 0; df < 4; ++df) {
      const char* vrow = sVb + (df * 16 + l15) * 128;
      va[df][0] = *reinterpret_cast<const bf16x8*>(vrow + ((l4 ^ swz) << 4));
      va[df][1] = *reinterpret_cast<const bf16x8*>(vrow + (((4 + l4) ^ swz) << 4));
    }

    // ---- lane-local softmax (one q-row per lane, log2 domain) ----
    // max over 16 values via v_max3 fusion (triple-nested fmaxf)
    float pm = fmax3(fmax3(s[0][0], s[0][1], s[0][2]),
                     fmax3(s[0][3], s[1][0], s[1][1]),
                     fmax3(s[1][2], s[1][3], s[2][0]));
    pm = fmax3(pm,
               fmax3(s[2][1], s[2][2], s[2][3]),
               fmax3(s[3][0], s[3][1], fmaxf(s[3][2], s[3][3])));
    pm = fmaxf(pm, __shfl_xor(pm, 16));
    pm = fmaxf(pm, __shfl_xor(pm, 32));
    if (!__all(pm - m <= 11.5f)) {  // T13 defer-max (log2 units)
      float mn = fmaxf(m, pm);
      float sc2 = fexp2(m - mn);
      m = mn;
      l *= sc2;
#pragma unroll
      for (int df = 0; df < 4; ++df) accO[df] *= sc2;
    }
    float ps = 0.f;
#pragma unroll
    for (int nf = 0; nf < 4; ++nf)
#pragma unroll
      for (int r = 0; r < 4; ++r) {
        float p = fexp2(s[nf][r] - m);
        s[nf][r] = p;
        ps += p;
      }
    ps += __shfl_xor(ps, 16);
    ps += __shfl_xor(ps, 32);
    l += ps;

    // ---- P -> per-wave LDS (row q=l15): 4x ds_write_b64, swizzled ----
#pragma unroll
    for (int nf = 0; nf < 4; ++nf) {
      bf16x4v pv;
      pv[0] = (__bf16)s[nf][0];
      pv[1] = (__bf16)s[nf][1];
      pv[2] = (__bf16)s[nf][2];
      pv[3] = (__bf16)s[nf][3];
      *reinterpret_cast<uint2*>(pb + l15 * 128 + ((nf * 32 + l4 * 8) ^ rx)) =
          __builtin_bit_cast(uint2, pv);
    }
    asm volatile("" ::: "memory");  // order P writes before P reads (TBAA insurance)
    // ---- PV: A = P[q=l15][k=key], B = V^T[key][d] ----
    bf16x8 ap0 = *reinterpret_cast<const bf16x8*>(pb + l15 * 128 + ((l4 * 16) ^ rx));
    bf16x8 ap1 = *reinterpret_cast<const bf16x8*>(pb + l15 * 128 + ((64 + l4 * 16) ^ rx));
#pragma unroll
    for (int df = 0; df < 4; ++df)
      accO[df] = MFMA16(ap1, va[df][1], MFMA16(ap0, va[df][0], accO[df]));

    __syncthreads();  // drains vmcnt(0): next tile landed; all waves done reading
    buf ^= 1;
  }

  // epilogue: lane holds O[q=q0+l4*4+r][d=df*16+l15]; l lives at lane l4*4+r
  float inv[4];
#pragma unroll
  for (int r = 0; r < 4; ++r) inv[r] = 1.f / __shfl(l, l4 * 4 + r);
#pragma unroll
  for (int df = 0; df < 4; ++df)
#pragma unroll
    for (int r = 0; r < 4; ++r) {
      int row = q0 + l4 * 4 + r;
      int col = h * HDc + df * 16 + l15;
      Ob[((size_t)b * TQc + row) * Dc + col] = bfbits(accO[df][r] * inv[r]);
    }
}

// ---------------------------------------------------------------------------
extern "C" void kernel_launch(void* const* d_in, const int* in_sizes, int n_in,
                              void* d_out, int out_size, void* d_ws, size_t ws_size,
                              hipStream_t stream) {
  const float* X  = (const float*)d_in[0];
  const float* E  = (const float*)d_in[1];
  const float* Wq = (const float*)d_in[2];
  const float* bq = (const float*)d_in[3];
  const float* Wk = (const float*)d_in[4];
  const float* bk = (const float*)d_in[5];
  const float* Wv = (const float*)d_in[6];
  const float* bv = (const float*)d_in[7];
  const float* Wo = (const float*)d_in[8];
  const float* bo = (const float*)d_in[9];
  float* out = (float*)d_out;
  char* ws = (char*)d_ws;

  const size_t MB = 1ull << 20;
  if (ws_size < 42 * MB) return;  // tripwire: reproduces stub failure signature

  ushort* Xb   = (ushort*)(ws + 0 * MB);   // [4096][1024] bf16
  ushort* Eb   = (ushort*)(ws + 8 * MB);   // [4096][1024]
  ushort* Wqt  = (ushort*)(ws + 16 * MB);  // [1024][1024]
  ushort* Wkvt = (ushort*)(ws + 18 * MB);  // [512][1024] (Wk^T | Wv^T)
  ushort* Wot  = (ushort*)(ws + 19 * MB);  // [1024][1024]
  ushort* Qb   = (ushort*)(ws + 21 * MB);  // [2][16][2048][64]
  ushort* Kb   = (ushort*)(ws + 29 * MB);  // [2][4][2048][64]
  ushort* Vt   = (ushort*)(ws + 31 * MB);  // [2][4][64][2048]
  ushort* Ob   = (ushort*)(ws + 33 * MB);  // [2][2048][1024]

  // 1. casts + weight transposes
  prep_k<<<dim3(8960), 256, 0, stream>>>(X, E, Wq, Wo, Wk, Wv, Xb, Eb, Wqt, Wot, Wkvt);
  // 2. Q-proj (+RoPE+scale) and KV-proj (K+RoPE, V^T) concurrently
  qkv_k<<<dim3(768), 256, 0, stream>>>(Xb, Eb, Wqt, Wkvt, bq, bk, bv, Qb, Kb, Vt);
  // 3. attention -> Ob
  attn_k<<<dim3(512), dim3(512), 0, stream>>>(Qb, Kb, Vt, Ob);
  // 4. output projection -> out (f32)
  oproj_k<<<dim3(512), 256, 0, stream>>>(Ob, Wot, bo, out);
}